// Round 14
// baseline (145.632 us; speedup 1.0000x reference)
//
#include <hip/hip_runtime.h>

typedef __bf16 bf16_t;
typedef __bf16 bf16x8 __attribute__((ext_vector_type(8)));
typedef __bf16 bf16x4 __attribute__((ext_vector_type(4)));
typedef float f32x4 __attribute__((ext_vector_type(4)));
typedef float f32x16 __attribute__((ext_vector_type(16)));
typedef unsigned int u32;
typedef unsigned int u32x2 __attribute__((ext_vector_type(2)));

#define GLB_AS(p) ((const __attribute__((address_space(1))) unsigned int*)(p))
#define LDS_AS(p) ((__attribute__((address_space(3))) unsigned int*)(p))

// rows per KV-split = 16 bh * 2048 q = 32768; 4 splits of 512 kv each
#define SPLIT_ROWS 32768
#define KLD 68   // K tile [32 kv][64 d] row stride (pad +4): ~0 conflicts (R9/R13-measured)
#define VLD 44   // V^T tile [64 d][32 kv] row stride (pad +12): ~0 conflicts (R9/R13-measured)

// ---------------- merged fp32 -> bf16 convert: inputs (scaled) + encoder ----------------
__global__ void cvt_both_kernel(const float* __restrict__ inA, bf16_t* __restrict__ outA, float scaleA,
                                const float* __restrict__ inB, bf16_t* __restrict__ outB)
{
    const int bid = blockIdx.x;
    const float* in;
    bf16_t* out;
    float scale;
    int i;
    if (bid < 2048) { in = inA; out = outA; scale = scaleA; i = (bid * 256 + threadIdx.x) * 4; }
    else            { in = inB; out = outB; scale = 1.0f;  i = ((bid - 2048) * 256 + threadIdx.x) * 4; }
    float4 v = *(const float4*)(in + i);
    bf16x4 o;
    o[0] = (bf16_t)(v.x * scale); o[1] = (bf16_t)(v.y * scale);
    o[2] = (bf16_t)(v.z * scale); o[3] = (bf16_t)(v.w * scale);
    *(bf16x4*)(out + i) = o;
}

// ---------------- merged weight transposes: f32 [R][C] -> bf16 [C][R], 5 jobs ----------------
__global__ void wtrans_all_kernel(const float* __restrict__ Wq, const float* __restrict__ Wk,
                                  const float* __restrict__ Wv, const float* __restrict__ W1,
                                  const float* __restrict__ W2, bf16_t* __restrict__ Wqkvt,
                                  bf16_t* __restrict__ W1t, bf16_t* __restrict__ W2t)
{
    const int j = blockIdx.x;
    const float* in;
    bf16_t* out;
    int R, C, bx, by;
    if (j < 768) {
        int k = j >> 8, l = j & 255;
        in = (k == 0) ? Wq : (k == 1) ? Wk : Wv;
        out = Wqkvt + k * 512 * 512;
        R = 512; C = 512; bx = l & 15; by = l >> 4;
    } else if (j < 1792) {
        int l = j - 768;
        in = W1; out = W1t; R = 512; C = 2048; bx = l % 64; by = l / 64;
    } else {
        int l = j - 1792;
        in = W2; out = W2t; R = 2048; C = 512; bx = l % 16; by = l / 16;
    }
    __shared__ float tile[32][33];
    const int tid = threadIdx.x;
    const int r0 = by * 32, c0 = bx * 32;
#pragma unroll
    for (int t = 0; t < 4; t++) {
        int r = t * 8 + (tid >> 5), c = tid & 31;
        tile[r][c] = in[(size_t)(r0 + r) * C + c0 + c];
    }
    __syncthreads();
#pragma unroll
    for (int t = 0; t < 4; t++) {
        int c = t * 8 + (tid >> 5), r = tid & 31;
        out[(size_t)(c0 + c) * R + r0 + r] = (bf16_t)tile[r][c];
    }
}

// ---------------- V transpose: QKV cols 1024..1535 -> Vt[bh][64][2048] ----------------
__global__ void vtrans_kernel(const bf16_t* __restrict__ qkv, bf16_t* __restrict__ vt)
{
    __shared__ bf16_t t[64][68];
    const int tid = threadIdx.x;
    const int lk0 = blockIdx.x * 64;
    const int bh = blockIdx.y, b = bh >> 3, h = bh & 7;
#pragma unroll
    for (int j = 0; j < 16; j++) {
        int e = j * 256 + tid;
        int lk_i = e >> 6, d = e & 63;
        t[lk_i][d] = qkv[(size_t)(b * 2048 + lk0 + lk_i) * 1536 + 1024 + h * 64 + d];
    }
    __syncthreads();
#pragma unroll
    for (int j = 0; j < 16; j++) {
        int e = j * 256 + tid;
        int d_i = e >> 6, lk = e & 63;
        vt[((size_t)bh * 64 + d_i) * 2048 + lk0 + lk] = t[lk][d_i];
    }
}

// ---------------- GEMM: C[M][N] = A[M][K] @ Bt[N][K]^T ----------------
template<int BM, bool SPLITA, bool BIAS, bool RELU, bool OUTBF16>
__global__ __launch_bounds__(256)
void gemm_kernel(const bf16_t* __restrict__ A0, const bf16_t* __restrict__ A1, int nsplit,
                 const bf16_t* __restrict__ Bt, const float* __restrict__ bias,
                 void* __restrict__ Cout, int K, int ldC)
{
    constexpr int FR = BM / 32;
    __shared__ __align__(16) bf16_t As[BM * 32];
    __shared__ __align__(16) bf16_t Bs[128 * 32];
    const int bm = blockIdx.x, bn = blockIdx.y;
    const bf16_t* A = (!SPLITA || bn < nsplit) ? A0 : A1;
    const int tid = threadIdx.x;
    const int lane = tid & 63;
    const int wid = tid >> 6;
    const int wr = wid >> 1, wc = wid & 1;

    f32x4 acc[FR][4] = {};

    const int cb = wid * 2;
    const int lbB0 = cb * 1024 + lane * 16;
    const int rowB0 = lbB0 >> 6, colB0 = (lbB0 & 63) >> 1;
    const int rowB1 = (lbB0 + 1024) >> 6, colB1 = ((lbB0 + 1024) & 63) >> 1;
    const int lbA0 = (BM == 128 ? cb * 1024 : wid * 1024) + lane * 16;
    const int rowA0 = lbA0 >> 6, colA0 = (lbA0 & 63) >> 1;
    const int rowA1 = (lbA0 + 1024) >> 6, colA1 = ((lbA0 + 1024) & 63) >> 1;

    const bf16_t* Abase = A + (size_t)(bm * BM) * K;
    const bf16_t* Bbase = Bt + (size_t)(bn * 128) * K;

    for (int k0 = 0; k0 < K; k0 += 32) {
        if constexpr (BM == 128) {
            __builtin_amdgcn_global_load_lds(GLB_AS(Abase + (size_t)rowA0 * K + k0 + colA0), LDS_AS(As + cb * 512), 16, 0, 0);
            __builtin_amdgcn_global_load_lds(GLB_AS(Abase + (size_t)rowA1 * K + k0 + colA1), LDS_AS(As + cb * 512 + 512), 16, 0, 0);
        } else {
            __builtin_amdgcn_global_load_lds(GLB_AS(Abase + (size_t)rowA0 * K + k0 + colA0), LDS_AS(As + wid * 512), 16, 0, 0);
        }
        __builtin_amdgcn_global_load_lds(GLB_AS(Bbase + (size_t)rowB0 * K + k0 + colB0), LDS_AS(Bs + cb * 512), 16, 0, 0);
        __builtin_amdgcn_global_load_lds(GLB_AS(Bbase + (size_t)rowB1 * K + k0 + colB1), LDS_AS(Bs + cb * 512 + 512), 16, 0, 0);
        __syncthreads();
        bf16x8 af[FR], bfr[4];
#pragma unroll
        for (int f = 0; f < FR; f++)
            af[f] = *(const bf16x8*)&As[(wr * (BM / 2) + f * 16 + (lane & 15)) * 32 + (lane >> 4) * 8];
#pragma unroll
        for (int f = 0; f < 4; f++)
            bfr[f] = *(const bf16x8*)&Bs[(wc * 64 + f * 16 + (lane & 15)) * 32 + (lane >> 4) * 8];
#pragma unroll
        for (int fr = 0; fr < FR; fr++)
#pragma unroll
            for (int fc = 0; fc < 4; fc++)
                acc[fr][fc] = __builtin_amdgcn_mfma_f32_16x16x32_bf16(af[fr], bfr[fc], acc[fr][fc], 0, 0, 0);
        __syncthreads();
    }

    const int rg = (lane >> 4) * 4, cl = lane & 15;
#pragma unroll
    for (int fc = 0; fc < 4; fc++) {
        const int col = bn * 128 + wc * 64 + fc * 16 + cl;
        float bv = 0.f;
        if (BIAS) bv = bias[col];
#pragma unroll
        for (int fr = 0; fr < FR; fr++) {
#pragma unroll
            for (int r = 0; r < 4; r++) {
                int rowg = bm * BM + wr * (BM / 2) + fr * 16 + rg + r;
                float v = acc[fr][fc][r] + bv;
                if (RELU) v = fmaxf(v, 0.f);
                if (OUTBF16) ((bf16_t*)Cout)[(size_t)rowg * ldC + col] = (bf16_t)v;
                else         ((float*)Cout)[(size_t)rowg * ldC + col] = v;
            }
        }
    }
}

// ---------------- flash attention: swapped-QK^T 32x32, 2-wave blocks, shared LDS ----------------
union BU { bf16x8 v; u32 d[4]; };

static __device__ __forceinline__ u32 pkbf(float a, float b)
{
    union { bf16_t h[2]; u32 w; } u;
    u.h[0] = (bf16_t)a; u.h[1] = (bf16_t)b;
    return u.w;
}

// permlane32_swap: x = {a.lo_lanes, b.lo_lanes}, y = {a.hi_lanes, b.hi_lanes}
static __device__ __forceinline__ void plswap(u32 a, u32 b, u32& x, u32& y)
{
#if __has_builtin(__builtin_amdgcn_permlane32_swap)
    u32x2 r = __builtin_amdgcn_permlane32_swap(a, b, false, false);
    x = r[0]; y = r[1];
#else
    const bool hi = (threadIdx.x & 32) != 0;
    u32 sb = __shfl_xor(b, 32), sa = __shfl_xor(a, 32);
    x = hi ? sb : a;
    y = hi ? b : sa;
#endif
}

// grid (32 qblocks, 16 bh, 4 kv-splits); 2 waves x 32 q-rows = 64 q/block; KVBLK=32.
// R13's math verbatim; restructured for overlap: 2-wave barrier groups, LDS 19968 B
// (epilogue transpose buffer UNIONED into Kst -> 8 blocks/CU resident, more independent
// barrier-groups per SIMD). Block-shared double-buffered K/V staging (128 thr x 2 passes
// x 16B coalesced). Softmax: P=mfma(K,Q), 15-fmax tree + permlane swap, exp2 domain,
// T13 defer-rescale, pack + 4 permlane -> PV B-frags, row-sum via ones-MFMA.
__global__ __launch_bounds__(128)
void flash_kernel(const bf16_t* __restrict__ QKV, const bf16_t* __restrict__ Vt,
                  bf16_t* __restrict__ Op01, bf16_t* __restrict__ Op23,
                  float2* __restrict__ ml)
{
    const int tid = threadIdx.x, lane = tid & 63, wid = tid >> 6;
    const int bh = blockIdx.y, b = bh >> 3, h = bh & 7;
    const int split = blockIdx.z;
    const int qbase = blockIdx.x * 64 + wid * 32;
    const int l31 = lane & 31, hi = lane >> 5;

    __shared__ __align__(16) bf16_t Kst[2][32 * KLD];   // 8704 B; reused as epilogue transpose
    __shared__ __align__(16) bf16_t Vst[2][64 * VLD];   // 11264 B

    const bf16_t* Qp = QKV + (size_t)(b * 2048 + qbase + l31) * 1536 + h * 64 + hi * 8;
    const bf16_t* Kbase = QKV + (size_t)(b * 2048) * 1536 + 512 + h * 64;
    const bf16_t* Vbase = Vt + (size_t)bh * 64 * 2048;

    // cooperative staging geometry: 128 threads x 2 passes x 16B per tile
    const int kr = tid >> 3, kc = (tid & 7) * 8;   // K rows kr, kr+16
    const int vr = tid >> 2, vc = (tid & 3) * 8;   // V^T rows vr, vr+32

    bf16x8 qf[4];
#pragma unroll
    for (int t = 0; t < 4; t++)
        qf[t] = *(const bf16x8*)(Qp + t * 16);

    bf16x8 ones;
#pragma unroll
    for (int e = 0; e < 8; e++) ones[e] = (bf16_t)1.0f;

    f32x16 acc0 = {}, acc1 = {}, accS = {};
    float mrun = -1e30f;

    const int kv0 = split * 512;

    // prologue: stage tile 0 into buf 0
    bf16x8 kreg0 = *(const bf16x8*)(Kbase + (size_t)(kv0 + kr) * 1536 + kc);
    bf16x8 kreg1 = *(const bf16x8*)(Kbase + (size_t)(kv0 + 16 + kr) * 1536 + kc);
    bf16x8 vreg0 = *(const bf16x8*)(Vbase + (size_t)vr * 2048 + kv0 + vc);
    bf16x8 vreg1 = *(const bf16x8*)(Vbase + (size_t)(32 + vr) * 2048 + kv0 + vc);
    *(bf16x8*)&Kst[0][kr * KLD + kc] = kreg0;
    *(bf16x8*)&Kst[0][(16 + kr) * KLD + kc] = kreg1;
    *(bf16x8*)&Vst[0][vr * VLD + vc] = vreg0;
    *(bf16x8*)&Vst[0][(32 + vr) * VLD + vc] = vreg1;
    __syncthreads();

    int buf = 0;
#pragma unroll 2
    for (int kt = kv0; kt < kv0 + 512; kt += 32) {
        const bool nxt = (kt + 32 < kv0 + 512);
        // issue next tile's coalesced loads (latency hides under compute)
        if (nxt) {
            kreg0 = *(const bf16x8*)(Kbase + (size_t)(kt + 32 + kr) * 1536 + kc);
            kreg1 = *(const bf16x8*)(Kbase + (size_t)(kt + 48 + kr) * 1536 + kc);
            vreg0 = *(const bf16x8*)(Vbase + (size_t)vr * 2048 + kt + 32 + vc);
            vreg1 = *(const bf16x8*)(Vbase + (size_t)(32 + vr) * 2048 + kt + 32 + vc);
        }

        // fragments from LDS[buf] (0-conflict padded layout)
        bf16x8 kf[4];
#pragma unroll
        for (int t = 0; t < 4; t++)
            kf[t] = *(const bf16x8*)&Kst[buf][l31 * KLD + hi * 8 + t * 16];
        bf16x8 vf00 = *(const bf16x8*)&Vst[buf][l31 * VLD + hi * 8];
        bf16x8 vf01 = *(const bf16x8*)&Vst[buf][l31 * VLD + 16 + hi * 8];
        bf16x8 vf10 = *(const bf16x8*)&Vst[buf][(32 + l31) * VLD + hi * 8];
        bf16x8 vf11 = *(const bf16x8*)&Vst[buf][(32 + l31) * VLD + 16 + hi * 8];

        f32x16 p = {};
        __builtin_amdgcn_s_setprio(1);
        p = __builtin_amdgcn_mfma_f32_32x32x16_bf16(kf[0], qf[0], p, 0, 0, 0);
        p = __builtin_amdgcn_mfma_f32_32x32x16_bf16(kf[1], qf[1], p, 0, 0, 0);
        p = __builtin_amdgcn_mfma_f32_32x32x16_bf16(kf[2], qf[2], p, 0, 0, 0);
        p = __builtin_amdgcn_mfma_f32_32x32x16_bf16(kf[3], qf[3], p, 0, 0, 0);
        __builtin_amdgcn_s_setprio(0);

        // tile max: in-register tree + permlane half-exchange
        float x0 = fmaxf(p[0], p[8]),  x1 = fmaxf(p[1], p[9]);
        float x2 = fmaxf(p[2], p[10]), x3 = fmaxf(p[3], p[11]);
        float x4 = fmaxf(p[4], p[12]), x5 = fmaxf(p[5], p[13]);
        float x6 = fmaxf(p[6], p[14]), x7 = fmaxf(p[7], p[15]);
        x0 = fmaxf(x0, x4); x1 = fmaxf(x1, x5); x2 = fmaxf(x2, x6); x3 = fmaxf(x3, x7);
        float cm = fmaxf(fmaxf(x0, x1), fmaxf(x2, x3));
        {
            u32 r0, r1;
            plswap(__float_as_uint(cm), __float_as_uint(cm), r0, r1);
            cm = fmaxf(__uint_as_float(r0), __uint_as_float(r1));
        }

        // T13 defer-rescale
        if (__any(cm > mrun + 12.0f)) {
            float mnew = fmaxf(mrun, cm);
            float fac = __builtin_amdgcn_exp2f(mrun - mnew);
#pragma unroll
            for (int i = 0; i < 16; i++) { acc0[i] *= fac; acc1[i] *= fac; accS[i] *= fac; }
            mrun = mnew;
        }

        float e[16];
#pragma unroll
        for (int i = 0; i < 16; i++) e[i] = __builtin_amdgcn_exp2f(p[i] - mrun);

        // pack to bf16 pairs; permlane half-swaps assemble both PV B-fragments
        u32 pk0 = pkbf(e[0], e[1]),   pk1 = pkbf(e[2], e[3]);
        u32 pk2 = pkbf(e[4], e[5]),   pk3 = pkbf(e[6], e[7]);
        u32 pk4 = pkbf(e[8], e[9]),   pk5 = pkbf(e[10], e[11]);
        u32 pk6 = pkbf(e[12], e[13]), pk7 = pkbf(e[14], e[15]);
        BU b0, b1;
        plswap(pk0, pk2, b0.d[0], b0.d[2]);
        plswap(pk1, pk3, b0.d[1], b0.d[3]);
        plswap(pk4, pk6, b1.d[0], b1.d[2]);
        plswap(pk5, pk7, b1.d[1], b1.d[3]);

        // PV + row-sum (ones-MFMA): O^T[d][q], accS rows all = softmax denominator
        __builtin_amdgcn_s_setprio(1);
        acc0 = __builtin_amdgcn_mfma_f32_32x32x16_bf16(vf00, b0.v, acc0, 0, 0, 0);
        acc0 = __builtin_amdgcn_mfma_f32_32x32x16_bf16(vf01, b1.v, acc0, 0, 0, 0);
        acc1 = __builtin_amdgcn_mfma_f32_32x32x16_bf16(vf10, b0.v, acc1, 0, 0, 0);
        acc1 = __builtin_amdgcn_mfma_f32_32x32x16_bf16(vf11, b1.v, acc1, 0, 0, 0);
        accS = __builtin_amdgcn_mfma_f32_32x32x16_bf16(ones, b0.v, accS, 0, 0, 0);
        accS = __builtin_amdgcn_mfma_f32_32x32x16_bf16(ones, b1.v, accS, 0, 0, 0);
        __builtin_amdgcn_s_setprio(0);

        // commit next tile into buf^1 (after this iter's LDS reads)
        if (nxt) {
            *(bf16x8*)&Kst[buf ^ 1][kr * KLD + kc] = kreg0;
            *(bf16x8*)&Kst[buf ^ 1][(16 + kr) * KLD + kc] = kreg1;
            *(bf16x8*)&Vst[buf ^ 1][vr * VLD + vc] = vreg0;
            *(bf16x8*)&Vst[buf ^ 1][(32 + vr) * VLD + vc] = vreg1;
        }
        __syncthreads();
        buf ^= 1;
    }

    // epilogue: per-wave transpose via LDS slice UNIONED into Kst (loop done; own slice only)
    const float lsum = accS[0];
    float inv = 1.f / lsum;
    bf16_t* tw = (bf16_t*)Kst + wid * (32 * KLD);
#pragma unroll
    for (int r = 0; r < 16; r++) {
        int drow = (r & 3) + 8 * (r >> 2) + 4 * hi;
        tw[l31 * KLD + drow]      = (bf16_t)(acc0[r] * inv);
        tw[l31 * KLD + 32 + drow] = (bf16_t)(acc1[r] * inv);
    }
    bf16_t* Op = (split < 2) ? Op01 + (size_t)split * SPLIT_ROWS * 64
                             : Op23 + (size_t)(split - 2) * SPLIT_ROWS * 64;
    const size_t rowbase = (size_t)bh * 2048 + qbase;
#pragma unroll
    for (int ps = 0; ps < 4; ps++) {
        int rr = (lane >> 3) + ps * 8;
        int cc = lane & 7;
        bf16x8 ov = *(const bf16x8*)&tw[rr * KLD + cc * 8];
        *(bf16x8*)(Op + (rowbase + rr) * 64 + cc * 8) = ov;
    }
    if (lane < 32)
        ml[(size_t)split * SPLIT_ROWS + rowbase + l31] = make_float2(mrun, lsum);
}

// ---------------- fused combine(4 splits) + residual-add + LayerNorm -> out1b bf16 ----------------
// grid 4096 rows; 128 threads x 4 dims. m in log2 units.
// NOTE: outb must NOT alias Op01/Op23 (R12 lesson: cross-block read/write race).
__global__ __launch_bounds__(128)
void combine_ln_kernel(const bf16_t* __restrict__ Op01, const bf16_t* __restrict__ Op23,
                       const float2* __restrict__ ml, const float* __restrict__ resid,
                       const float* __restrict__ g, const float* __restrict__ bta,
                       bf16_t* __restrict__ outb)
{
    const int row = blockIdx.x;            // b*2048 + q
    const int tid = threadIdx.x;
    const int b = row >> 11, q = row & 2047;
    const int d = tid * 4, h = d >> 6, dd = d & 63;
    const size_t prow = ((size_t)(b * 8 + h)) * 2048 + q;

    float2 m0 = ml[prow];
    float2 m1 = ml[SPLIT_ROWS + prow];
    float2 m2 = ml[2 * SPLIT_ROWS + prow];
    float2 m3 = ml[3 * SPLIT_ROWS + prow];
    float M = fmaxf(fmaxf(m0.x, m1.x), fmaxf(m2.x, m3.x));
    float w0 = m0.y * __builtin_amdgcn_exp2f(m0.x - M);
    float w1 = m1.y * __builtin_amdgcn_exp2f(m1.x - M);
    float w2 = m2.y * __builtin_amdgcn_exp2f(m2.x - M);
    float w3 = m3.y * __builtin_amdgcn_exp2f(m3.x - M);
    float winv = 1.f / (w0 + w1 + w2 + w3);

    bf16x4 p0 = *(const bf16x4*)(Op01 + prow * 64 + dd);
    bf16x4 p1 = *(const bf16x4*)(Op01 + (SPLIT_ROWS + prow) * 64 + dd);
    bf16x4 p2 = *(const bf16x4*)(Op23 + prow * 64 + dd);
    bf16x4 p3 = *(const bf16x4*)(Op23 + (SPLIT_ROWS + prow) * 64 + dd);
    float4 rv = ((const float4*)resid)[row * 128 + tid];

    float x0 = (w0 * (float)p0[0] + w1 * (float)p1[0] + w2 * (float)p2[0] + w3 * (float)p3[0]) * winv + rv.x;
    float x1 = (w0 * (float)p0[1] + w1 * (float)p1[1] + w2 * (float)p2[1] + w3 * (float)p3[1]) * winv + rv.y;
    float x2 = (w0 * (float)p0[2] + w1 * (float)p1[2] + w2 * (float)p2[2] + w3 * (float)p3[2]) * winv + rv.z;
    float x3 = (w0 * (float)p0[3] + w1 * (float)p1[3] + w2 * (float)p2[3] + w3 * (float)p3[3]) * winv + rv.w;

    float s = x0 + x1 + x2 + x3;
    float sq = x0 * x0 + x1 * x1 + x2 * x2 + x3 * x3;
#pragma unroll
    for (int dl = 1; dl < 64; dl <<= 1) { s += __shfl_xor(s, dl); sq += __shfl_xor(sq, dl); }
    __shared__ float red[2][2];
    const int wid = tid >> 6;
    if ((tid & 63) == 0) { red[wid][0] = s; red[wid][1] = sq; }
    __syncthreads();
    s = red[0][0] + red[1][0];
    sq = red[0][1] + red[1][1];
    float mu = s * (1.f / 512.f);
    float var = sq * (1.f / 512.f) - mu * mu;
    float rstd = rsqrtf(var + 1e-5f);
    const float4 gv = ((const float4*)g)[tid];
    const float4 bv = ((const float4*)bta)[tid];
    bf16x4 o;
    o[0] = (bf16_t)((x0 - mu) * rstd * gv.x + bv.x);
    o[1] = (bf16_t)((x1 - mu) * rstd * gv.y + bv.y);
    o[2] = (bf16_t)((x2 - mu) * rstd * gv.z + bv.z);
    o[3] = (bf16_t)((x3 - mu) * rstd * gv.w + bv.w);
    *(bf16x4*)(outb + (size_t)row * 512 + tid * 4) = o;
}

// ---------------- fused residual-add + LayerNorm (D=512) ----------------
template<bool RESBF>
__global__ __launch_bounds__(128)
void add_ln_kernel(const float* __restrict__ a, const void* __restrict__ res,
                   const float* __restrict__ g, const float* __restrict__ bta,
                   float* outf, bf16_t* outb)
{
    const int row = blockIdx.x, tid = threadIdx.x;
    const float4* a4 = (const float4*)(a + (size_t)row * 512);
    float4 av = a4[tid];
    float r0, r1, r2, r3;
    if (RESBF) {
        bf16x4 rv = ((const bf16x4*)res)[row * 128 + tid];
        r0 = (float)rv[0]; r1 = (float)rv[1]; r2 = (float)rv[2]; r3 = (float)rv[3];
    } else {
        float4 rv = ((const float4*)res)[row * 128 + tid];
        r0 = rv.x; r1 = rv.y; r2 = rv.z; r3 = rv.w;
    }
    float x0 = av.x + r0, x1 = av.y + r1, x2 = av.z + r2, x3 = av.w + r3;
    float s = x0 + x1 + x2 + x3;
    float sq = x0 * x0 + x1 * x1 + x2 * x2 + x3 * x3;
#pragma unroll
    for (int d = 1; d < 64; d <<= 1) { s += __shfl_xor(s, d); sq += __shfl_xor(sq, d); }
    __shared__ float red[2][2];
    const int wid = tid >> 6;
    if ((tid & 63) == 0) { red[wid][0] = s; red[wid][1] = sq; }
    __syncthreads();
    s = red[0][0] + red[1][0];
    sq = red[0][1] + red[1][1];
    float mu = s * (1.f / 512.f);
    float var = sq * (1.f / 512.f) - mu * mu;
    float rstd = rsqrtf(var + 1e-5f);
    const float4* g4 = (const float4*)g;
    const float4* b4 = (const float4*)bta;
    float4 gv = g4[tid], bv = b4[tid];
    float4 y;
    y.x = (x0 - mu) * rstd * gv.x + bv.x;
    y.y = (x1 - mu) * rstd * gv.y + bv.y;
    y.z = (x2 - mu) * rstd * gv.z + bv.z;
    y.w = (x3 - mu) * rstd * gv.w + bv.w;
    if (outf) ((float4*)(outf + (size_t)row * 512))[tid] = y;
    if (outb) {
        bf16x4 o;
        o[0] = (bf16_t)y.x; o[1] = (bf16_t)y.y; o[2] = (bf16_t)y.z; o[3] = (bf16_t)y.w;
        *(bf16x4*)(outb + (size_t)row * 512 + tid * 4) = o;
    }
}

// ---------------- orchestration ----------------
// Workspace arena (29.5 MB high-water; lifetime-safe aliasing) — R13 layout (verified):
//   0- 2 MB : W1t    (A->F)
//   2- 4 MB : W2t    (A->G)
//   4-12 MB : Xb(4-8)+Eb(8-12) (A->B); then Op01 splits 0-1 (D->E); then Hb[0:8MB] (F->G)
//  12-24 MB : QKVb   (B->D); then Hb[8:16MB] at 12-20 (F->G); 20-24 free
//  24-28 MB : Vtb    (C->D); then out1b (E->H)   <-- disjoint from Op01/Op23
//  28-29.5  : Wqkvt  (A->B); then ml 1MB (4x32768 float2) (D->E)
// d_out: Op23 splits 2-3 (D->E); then FF f32 (G->H, in-place LN2).
extern "C" void kernel_launch(void* const* d_in, const int* in_sizes, int n_in,
                              void* d_out, int out_size, void* d_ws, size_t ws_size,
                              hipStream_t stream)
{
    const float* inputs = (const float*)d_in[0];
    const float* encx   = (const float*)d_in[1];
    const float* Wq     = (const float*)d_in[2];
    const float* Wk     = (const float*)d_in[3];
    const float* Wv     = (const float*)d_in[4];
    const float* ln1g   = (const float*)d_in[5];
    const float* ln1b   = (const float*)d_in[6];
    const float* W1     = (const float*)d_in[7];
    const float* b1     = (const float*)d_in[8];
    const float* W2     = (const float*)d_in[9];
    const float* b2     = (const float*)d_in[10];
    const float* ln2g   = (const float*)d_in[11];
    const float* ln2b   = (const float*)d_in[12];

    char* ws = (char*)d_ws;
    const size_t MB = 1u << 20;
    bf16_t* W1t   = (bf16_t*)(ws);
    bf16_t* W2t   = (bf16_t*)(ws + 2 * MB);
    bf16_t* Xb    = (bf16_t*)(ws + 4 * MB);
    bf16_t* Op01  = (bf16_t*)(ws + 4 * MB);       // 8 MB, aliases Xb+Eb (dead after QKV gemm)
    bf16_t* Hb    = (bf16_t*)(ws + 4 * MB);       // 16 MB @4-20, aliases Op01(dead after E)+QKVb
    bf16_t* Eb    = (bf16_t*)(ws + 8 * MB);
    bf16_t* QKVb  = (bf16_t*)(ws + 12 * MB);
    bf16_t* Vtb   = (bf16_t*)(ws + 24 * MB);
    bf16_t* out1b = (bf16_t*)(ws + 24 * MB);      // 4 MB, aliases Vtb (dead after flash)
    bf16_t* Wqkvt = (bf16_t*)(ws + 28 * MB);
    float2* mlbuf = (float2*)(ws + 28 * MB);      // 1 MB, aliases Wqkvt (dead after QKV gemm)
    bf16_t* Op23  = (bf16_t*)d_out;               // 8 MB, d_out unused until combine_ln
    float*  FF    = (float*)d_out;                // FF (G->H, consumed in-place by ln2)

    // A. merged convert (Q path folds 0.125*log2(e)) + merged weight transposes
    cvt_both_kernel<<<4096, 256, 0, stream>>>(inputs, Xb, 0.125f * 1.44269504f, encx, Eb);
    wtrans_all_kernel<<<2816, 256, 0, stream>>>(Wq, Wk, Wv, W1, W2, Wqkvt, W1t, W2t);
    // B. fused QKV projection: C[4096][1536] (BM=128: 384 blocks, full A-staging efficiency)
    gemm_kernel<128, true, false, false, true><<<dim3(32, 12), 256, 0, stream>>>(
        Xb, Eb, 4, Wqkvt, nullptr, QKVb, 512, 1536);
    // C. V -> Vt[bh][64][2048]
    vtrans_kernel<<<dim3(32, 16), 256, 0, stream>>>(QKVb, Vtb);
    // D. flash attention (kv-split 4, 2-wave blocks, 8 blocks/CU) -> partials
    flash_kernel<<<dim3(32, 16, 4), 128, 0, stream>>>(QKVb, Vtb, Op01, Op23, mlbuf);
    // E. fused combine + LN1: out1 = LN(O + inputs) -> bf16 at 24-28 MB
    combine_ln_kernel<<<4096, 128, 0, stream>>>(Op01, Op23, mlbuf, inputs, ln1g, ln1b, out1b);
    // F. H = relu(out1 @ W1 + b1)  [4096][2048] bf16 -> 4-20 MB
    gemm_kernel<128, false, true, true, true><<<dim3(32, 16), 256, 0, stream>>>(
        out1b, nullptr, 0, W1t, b1, Hb, 512, 2048);
    // G. FF = H @ W2 + b2  [4096][512] f32 -> d_out
    gemm_kernel<64, false, true, false, false><<<dim3(64, 4), 256, 0, stream>>>(
        Hb, nullptr, 0, W2t, b2, FF, 2048, 512);
    // H. final = LN(FF + out1b) -> d_out (in-place, row-local)
    add_ln_kernel<true><<<4096, 128, 0, stream>>>(FF, out1b, ln2g, ln2b, (float*)d_out, nullptr);
}

// Round 15
// 132.791 us; speedup vs baseline: 1.0967x; 1.0967x over previous
//
#include <hip/hip_runtime.h>

typedef __bf16 bf16_t;
typedef __bf16 bf16x8 __attribute__((ext_vector_type(8)));
typedef __bf16 bf16x4 __attribute__((ext_vector_type(4)));
typedef float f32x4 __attribute__((ext_vector_type(4)));
typedef float f32x16 __attribute__((ext_vector_type(16)));
typedef unsigned int u32;
typedef unsigned int u32x2 __attribute__((ext_vector_type(2)));

#define GLB_AS(p) ((const __attribute__((address_space(1))) unsigned int*)(p))
#define LDS_AS(p) ((__attribute__((address_space(3))) unsigned int*)(p))

// rows per KV-split = 16 bh * 2048 q = 32768; 4 splits of 512 kv each
#define SPLIT_ROWS 32768
#define KLD 68   // K tile [32 kv][64 d] row stride (pad +4): ~0 conflicts (R9/R13-measured)
#define VLD 44   // V^T tile [64 d][32 kv] row stride (pad +12): ~0 conflicts (R9/R13-measured)

// ---------------- merged fp32 -> bf16 convert: inputs (scaled) + encoder ----------------
__global__ void cvt_both_kernel(const float* __restrict__ inA, bf16_t* __restrict__ outA, float scaleA,
                                const float* __restrict__ inB, bf16_t* __restrict__ outB)
{
    const int bid = blockIdx.x;
    const float* in;
    bf16_t* out;
    float scale;
    int i;
    if (bid < 2048) { in = inA; out = outA; scale = scaleA; i = (bid * 256 + threadIdx.x) * 4; }
    else            { in = inB; out = outB; scale = 1.0f;  i = ((bid - 2048) * 256 + threadIdx.x) * 4; }
    float4 v = *(const float4*)(in + i);
    bf16x4 o;
    o[0] = (bf16_t)(v.x * scale); o[1] = (bf16_t)(v.y * scale);
    o[2] = (bf16_t)(v.z * scale); o[3] = (bf16_t)(v.w * scale);
    *(bf16x4*)(out + i) = o;
}

// ---------------- merged weight transposes: f32 [R][C] -> bf16 [C][R], 5 jobs ----------------
__global__ void wtrans_all_kernel(const float* __restrict__ Wq, const float* __restrict__ Wk,
                                  const float* __restrict__ Wv, const float* __restrict__ W1,
                                  const float* __restrict__ W2, bf16_t* __restrict__ Wqkvt,
                                  bf16_t* __restrict__ W1t, bf16_t* __restrict__ W2t)
{
    const int j = blockIdx.x;
    const float* in;
    bf16_t* out;
    int R, C, bx, by;
    if (j < 768) {
        int k = j >> 8, l = j & 255;
        in = (k == 0) ? Wq : (k == 1) ? Wk : Wv;
        out = Wqkvt + k * 512 * 512;
        R = 512; C = 512; bx = l & 15; by = l >> 4;
    } else if (j < 1792) {
        int l = j - 768;
        in = W1; out = W1t; R = 512; C = 2048; bx = l % 64; by = l / 64;
    } else {
        int l = j - 1792;
        in = W2; out = W2t; R = 2048; C = 512; bx = l % 16; by = l / 16;
    }
    __shared__ float tile[32][33];
    const int tid = threadIdx.x;
    const int r0 = by * 32, c0 = bx * 32;
#pragma unroll
    for (int t = 0; t < 4; t++) {
        int r = t * 8 + (tid >> 5), c = tid & 31;
        tile[r][c] = in[(size_t)(r0 + r) * C + c0 + c];
    }
    __syncthreads();
#pragma unroll
    for (int t = 0; t < 4; t++) {
        int c = t * 8 + (tid >> 5), r = tid & 31;
        out[(size_t)(c0 + c) * R + r0 + r] = (bf16_t)tile[r][c];
    }
}

// ---------------- V transpose: QKV cols 1024..1535 -> Vt[bh][64][2048] ----------------
__global__ void vtrans_kernel(const bf16_t* __restrict__ qkv, bf16_t* __restrict__ vt)
{
    __shared__ bf16_t t[64][68];
    const int tid = threadIdx.x;
    const int lk0 = blockIdx.x * 64;
    const int bh = blockIdx.y, b = bh >> 3, h = bh & 7;
#pragma unroll
    for (int j = 0; j < 16; j++) {
        int e = j * 256 + tid;
        int lk_i = e >> 6, d = e & 63;
        t[lk_i][d] = qkv[(size_t)(b * 2048 + lk0 + lk_i) * 1536 + 1024 + h * 64 + d];
    }
    __syncthreads();
#pragma unroll
    for (int j = 0; j < 16; j++) {
        int e = j * 256 + tid;
        int d_i = e >> 6, lk = e & 63;
        vt[((size_t)bh * 64 + d_i) * 2048 + lk0 + lk] = t[lk][d_i];
    }
}

// ---------------- GEMM: C[M][N] = A[M][K] @ Bt[N][K]^T ----------------
// BM x 128 tile, BK=32, 4 waves; T3-minimum 2-phase: double-buffered LDS, next tile's
// global_load_lds issued BEFORE compute, ONE barrier per K-step (drains vmcnt+lgkm).
template<int BM, bool SPLITA, bool BIAS, bool RELU, bool OUTBF16>
__global__ __launch_bounds__(256)
void gemm_kernel(const bf16_t* __restrict__ A0, const bf16_t* __restrict__ A1, int nsplit,
                 const bf16_t* __restrict__ Bt, const float* __restrict__ bias,
                 void* __restrict__ Cout, int K, int ldC)
{
    constexpr int FR = BM / 32;
    __shared__ __align__(16) bf16_t As[2][BM * 32];
    __shared__ __align__(16) bf16_t Bs[2][128 * 32];
    const int bm = blockIdx.x, bn = blockIdx.y;
    const bf16_t* A = (!SPLITA || bn < nsplit) ? A0 : A1;
    const int tid = threadIdx.x;
    const int lane = tid & 63;
    const int wid = tid >> 6;
    const int wr = wid >> 1, wc = wid & 1;

    f32x4 acc[FR][4] = {};

    const int cb = wid * 2;
    const int lbB0 = cb * 1024 + lane * 16;
    const int rowB0 = lbB0 >> 6, colB0 = (lbB0 & 63) >> 1;
    const int rowB1 = (lbB0 + 1024) >> 6, colB1 = ((lbB0 + 1024) & 63) >> 1;
    const int lbA0 = (BM == 128 ? cb * 1024 : wid * 1024) + lane * 16;
    const int rowA0 = lbA0 >> 6, colA0 = (lbA0 & 63) >> 1;
    const int rowA1 = (lbA0 + 1024) >> 6, colA1 = ((lbA0 + 1024) & 63) >> 1;

    const bf16_t* Abase = A + (size_t)(bm * BM) * K;
    const bf16_t* Bbase = Bt + (size_t)(bn * 128) * K;

    // stage(k0 -> buf)
    auto stage = [&](int k0, int b_) {
        if constexpr (BM == 128) {
            __builtin_amdgcn_global_load_lds(GLB_AS(Abase + (size_t)rowA0 * K + k0 + colA0), LDS_AS(&As[b_][cb * 512]), 16, 0, 0);
            __builtin_amdgcn_global_load_lds(GLB_AS(Abase + (size_t)rowA1 * K + k0 + colA1), LDS_AS(&As[b_][cb * 512 + 512]), 16, 0, 0);
        } else {
            __builtin_amdgcn_global_load_lds(GLB_AS(Abase + (size_t)rowA0 * K + k0 + colA0), LDS_AS(&As[b_][wid * 512]), 16, 0, 0);
        }
        __builtin_amdgcn_global_load_lds(GLB_AS(Bbase + (size_t)rowB0 * K + k0 + colB0), LDS_AS(&Bs[b_][cb * 512]), 16, 0, 0);
        __builtin_amdgcn_global_load_lds(GLB_AS(Bbase + (size_t)rowB1 * K + k0 + colB1), LDS_AS(&Bs[b_][cb * 512 + 512]), 16, 0, 0);
    };

    stage(0, 0);
    __syncthreads();

    int cur = 0;
    for (int k0 = 0; k0 < K; k0 += 32) {
        // phase 1: issue next tile's loads into buf^1 (in flight across compute)
        if (k0 + 32 < K) stage(k0 + 32, cur ^ 1);

        // phase 2: compute current tile
        bf16x8 af[FR], bfr[4];
#pragma unroll
        for (int f = 0; f < FR; f++)
            af[f] = *(const bf16x8*)&As[cur][(wr * (BM / 2) + f * 16 + (lane & 15)) * 32 + (lane >> 4) * 8];
#pragma unroll
        for (int f = 0; f < 4; f++)
            bfr[f] = *(const bf16x8*)&Bs[cur][(wc * 64 + f * 16 + (lane & 15)) * 32 + (lane >> 4) * 8];
#pragma unroll
        for (int fr = 0; fr < FR; fr++)
#pragma unroll
            for (int fc = 0; fc < 4; fc++)
                acc[fr][fc] = __builtin_amdgcn_mfma_f32_16x16x32_bf16(af[fr], bfr[fc], acc[fr][fc], 0, 0, 0);

        // one barrier per K-step (implicit waitcnt drains the buf^1 loads)
        __syncthreads();
        cur ^= 1;
    }

    const int rg = (lane >> 4) * 4, cl = lane & 15;
#pragma unroll
    for (int fc = 0; fc < 4; fc++) {
        const int col = bn * 128 + wc * 64 + fc * 16 + cl;
        float bv = 0.f;
        if (BIAS) bv = bias[col];
#pragma unroll
        for (int fr = 0; fr < FR; fr++) {
#pragma unroll
            for (int r = 0; r < 4; r++) {
                int rowg = bm * BM + wr * (BM / 2) + fr * 16 + rg + r;
                float v = acc[fr][fc][r] + bv;
                if (RELU) v = fmaxf(v, 0.f);
                if (OUTBF16) ((bf16_t*)Cout)[(size_t)rowg * ldC + col] = (bf16_t)v;
                else         ((float*)Cout)[(size_t)rowg * ldC + col] = v;
            }
        }
    }
}

// ---------------- flash attention: swapped-QK^T 32x32, block-shared LDS (R13, proven) ----------------
union BU { bf16x8 v; u32 d[4]; };

static __device__ __forceinline__ u32 pkbf(float a, float b)
{
    union { bf16_t h[2]; u32 w; } u;
    u.h[0] = (bf16_t)a; u.h[1] = (bf16_t)b;
    return u.w;
}

// permlane32_swap: x = {a.lo_lanes, b.lo_lanes}, y = {a.hi_lanes, b.hi_lanes}
static __device__ __forceinline__ void plswap(u32 a, u32 b, u32& x, u32& y)
{
#if __has_builtin(__builtin_amdgcn_permlane32_swap)
    u32x2 r = __builtin_amdgcn_permlane32_swap(a, b, false, false);
    x = r[0]; y = r[1];
#else
    const bool hi = (threadIdx.x & 32) != 0;
    u32 sb = __shfl_xor(b, 32), sa = __shfl_xor(a, 32);
    x = hi ? sb : a;
    y = hi ? b : sa;
#endif
}

// grid (16 qblocks, 16 bh, 4 kv-splits); 4 waves x 32 q-rows = 128 q/block; KVBLK=32.
// R13 verbatim (43 µs measured): block-shared double-buffered K/V staging, in-register
// softmax (P=mfma(K,Q), 15-fmax tree + permlane swap, exp2 domain, T13 defer-rescale,
// pack + 4 permlane -> PV B-frags, row-sum via ones-MFMA). C-row: (r&3)+8*(r>>2)+4*hi.
__global__ __launch_bounds__(256)
void flash_kernel(const bf16_t* __restrict__ QKV, const bf16_t* __restrict__ Vt,
                  bf16_t* __restrict__ Op01, bf16_t* __restrict__ Op23,
                  float2* __restrict__ ml)
{
    const int tid = threadIdx.x, lane = tid & 63, wid = tid >> 6;
    const int bh = blockIdx.y, b = bh >> 3, h = bh & 7;
    const int split = blockIdx.z;
    const int qbase = blockIdx.x * 128 + wid * 32;
    const int l31 = lane & 31, hi = lane >> 5;

    __shared__ __align__(16) bf16_t Kst[2][32 * KLD];
    __shared__ __align__(16) bf16_t Vst[2][64 * VLD];
    __shared__ __align__(16) bf16_t tlds[4][32 * 68];
    bf16_t* tw = &tlds[wid][0];

    const bf16_t* Qp = QKV + (size_t)(b * 2048 + qbase + l31) * 1536 + h * 64 + hi * 8;
    const bf16_t* Kbase = QKV + (size_t)(b * 2048) * 1536 + 512 + h * 64;
    const bf16_t* Vbase = Vt + (size_t)bh * 64 * 2048;

    const int kr = tid >> 3, kc = (tid & 7) * 8;   // K: 8 thr/row, 32 rows
    const int vr = tid >> 2, vc = (tid & 3) * 8;   // V^T: 4 thr/row, 64 rows

    bf16x8 qf[4];
#pragma unroll
    for (int t = 0; t < 4; t++)
        qf[t] = *(const bf16x8*)(Qp + t * 16);

    bf16x8 ones;
#pragma unroll
    for (int e = 0; e < 8; e++) ones[e] = (bf16_t)1.0f;

    f32x16 acc0 = {}, acc1 = {}, accS = {};
    float mrun = -1e30f;

    const int kv0 = split * 512;

    bf16x8 kreg = *(const bf16x8*)(Kbase + (size_t)(kv0 + kr) * 1536 + kc);
    bf16x8 vreg = *(const bf16x8*)(Vbase + (size_t)vr * 2048 + kv0 + vc);
    *(bf16x8*)&Kst[0][kr * KLD + kc] = kreg;
    *(bf16x8*)&Vst[0][vr * VLD + vc] = vreg;
    __syncthreads();

    int buf = 0;
#pragma unroll 2
    for (int kt = kv0; kt < kv0 + 512; kt += 32) {
        const bool nxt = (kt + 32 < kv0 + 512);
        if (nxt) {
            kreg = *(const bf16x8*)(Kbase + (size_t)(kt + 32 + kr) * 1536 + kc);
            vreg = *(const bf16x8*)(Vbase + (size_t)vr * 2048 + kt + 32 + vc);
        }

        bf16x8 kf[4];
#pragma unroll
        for (int t = 0; t < 4; t++)
            kf[t] = *(const bf16x8*)&Kst[buf][l31 * KLD + hi * 8 + t * 16];
        bf16x8 vf00 = *(const bf16x8*)&Vst[buf][l31 * VLD + hi * 8];
        bf16x8 vf01 = *(const bf16x8*)&Vst[buf][l31 * VLD + 16 + hi * 8];
        bf16x8 vf10 = *(const bf16x8*)&Vst[buf][(32 + l31) * VLD + hi * 8];
        bf16x8 vf11 = *(const bf16x8*)&Vst[buf][(32 + l31) * VLD + 16 + hi * 8];

        f32x16 p = {};
        __builtin_amdgcn_s_setprio(1);
        p = __builtin_amdgcn_mfma_f32_32x32x16_bf16(kf[0], qf[0], p, 0, 0, 0);
        p = __builtin_amdgcn_mfma_f32_32x32x16_bf16(kf[1], qf[1], p, 0, 0, 0);
        p = __builtin_amdgcn_mfma_f32_32x32x16_bf16(kf[2], qf[2], p, 0, 0, 0);
        p = __builtin_amdgcn_mfma_f32_32x32x16_bf16(kf[3], qf[3], p, 0, 0, 0);
        __builtin_amdgcn_s_setprio(0);

        float x0 = fmaxf(p[0], p[8]),  x1 = fmaxf(p[1], p[9]);
        float x2 = fmaxf(p[2], p[10]), x3 = fmaxf(p[3], p[11]);
        float x4 = fmaxf(p[4], p[12]), x5 = fmaxf(p[5], p[13]);
        float x6 = fmaxf(p[6], p[14]), x7 = fmaxf(p[7], p[15]);
        x0 = fmaxf(x0, x4); x1 = fmaxf(x1, x5); x2 = fmaxf(x2, x6); x3 = fmaxf(x3, x7);
        float cm = fmaxf(fmaxf(x0, x1), fmaxf(x2, x3));
        {
            u32 r0, r1;
            plswap(__float_as_uint(cm), __float_as_uint(cm), r0, r1);
            cm = fmaxf(__uint_as_float(r0), __uint_as_float(r1));
        }

        if (__any(cm > mrun + 12.0f)) {
            float mnew = fmaxf(mrun, cm);
            float fac = __builtin_amdgcn_exp2f(mrun - mnew);
#pragma unroll
            for (int i = 0; i < 16; i++) { acc0[i] *= fac; acc1[i] *= fac; accS[i] *= fac; }
            mrun = mnew;
        }

        float e[16];
#pragma unroll
        for (int i = 0; i < 16; i++) e[i] = __builtin_amdgcn_exp2f(p[i] - mrun);

        u32 pk0 = pkbf(e[0], e[1]),   pk1 = pkbf(e[2], e[3]);
        u32 pk2 = pkbf(e[4], e[5]),   pk3 = pkbf(e[6], e[7]);
        u32 pk4 = pkbf(e[8], e[9]),   pk5 = pkbf(e[10], e[11]);
        u32 pk6 = pkbf(e[12], e[13]), pk7 = pkbf(e[14], e[15]);
        BU b0, b1;
        plswap(pk0, pk2, b0.d[0], b0.d[2]);
        plswap(pk1, pk3, b0.d[1], b0.d[3]);
        plswap(pk4, pk6, b1.d[0], b1.d[2]);
        plswap(pk5, pk7, b1.d[1], b1.d[3]);

        __builtin_amdgcn_s_setprio(1);
        acc0 = __builtin_amdgcn_mfma_f32_32x32x16_bf16(vf00, b0.v, acc0, 0, 0, 0);
        acc0 = __builtin_amdgcn_mfma_f32_32x32x16_bf16(vf01, b1.v, acc0, 0, 0, 0);
        acc1 = __builtin_amdgcn_mfma_f32_32x32x16_bf16(vf10, b0.v, acc1, 0, 0, 0);
        acc1 = __builtin_amdgcn_mfma_f32_32x32x16_bf16(vf11, b1.v, acc1, 0, 0, 0);
        accS = __builtin_amdgcn_mfma_f32_32x32x16_bf16(ones, b0.v, accS, 0, 0, 0);
        accS = __builtin_amdgcn_mfma_f32_32x32x16_bf16(ones, b1.v, accS, 0, 0, 0);
        __builtin_amdgcn_s_setprio(0);

        if (nxt) {
            *(bf16x8*)&Kst[buf ^ 1][kr * KLD + kc] = kreg;
            *(bf16x8*)&Vst[buf ^ 1][vr * VLD + vc] = vreg;
        }
        __syncthreads();
        buf ^= 1;
    }

    const float lsum = accS[0];
    float inv = 1.f / lsum;
#pragma unroll
    for (int r = 0; r < 16; r++) {
        int drow = (r & 3) + 8 * (r >> 2) + 4 * hi;
        tw[l31 * 68 + drow]      = (bf16_t)(acc0[r] * inv);
        tw[l31 * 68 + 32 + drow] = (bf16_t)(acc1[r] * inv);
    }
    bf16_t* Op = (split < 2) ? Op01 + (size_t)split * SPLIT_ROWS * 64
                             : Op23 + (size_t)(split - 2) * SPLIT_ROWS * 64;
    const size_t rowbase = (size_t)bh * 2048 + qbase;
#pragma unroll
    for (int ps = 0; ps < 4; ps++) {
        int rr = (lane >> 3) + ps * 8;
        int cc = lane & 7;
        bf16x8 ov = *(const bf16x8*)&tw[rr * 68 + cc * 8];
        *(bf16x8*)(Op + (rowbase + rr) * 64 + cc * 8) = ov;
    }
    if (lane < 32)
        ml[(size_t)split * SPLIT_ROWS + rowbase + l31] = make_float2(mrun, lsum);
}

// ---------------- fused combine(4 splits) + residual-add + LayerNorm -> out1b bf16 ----------------
// NOTE: outb must NOT alias Op01/Op23 (R12 lesson: cross-block read/write race).
__global__ __launch_bounds__(128)
void combine_ln_kernel(const bf16_t* __restrict__ Op01, const bf16_t* __restrict__ Op23,
                       const float2* __restrict__ ml, const float* __restrict__ resid,
                       const float* __restrict__ g, const float* __restrict__ bta,
                       bf16_t* __restrict__ outb)
{
    const int row = blockIdx.x;            // b*2048 + q
    const int tid = threadIdx.x;
    const int b = row >> 11, q = row & 2047;
    const int d = tid * 4, h = d >> 6, dd = d & 63;
    const size_t prow = ((size_t)(b * 8 + h)) * 2048 + q;

    float2 m0 = ml[prow];
    float2 m1 = ml[SPLIT_ROWS + prow];
    float2 m2 = ml[2 * SPLIT_ROWS + prow];
    float2 m3 = ml[3 * SPLIT_ROWS + prow];
    float M = fmaxf(fmaxf(m0.x, m1.x), fmaxf(m2.x, m3.x));
    float w0 = m0.y * __builtin_amdgcn_exp2f(m0.x - M);
    float w1 = m1.y * __builtin_amdgcn_exp2f(m1.x - M);
    float w2 = m2.y * __builtin_amdgcn_exp2f(m2.x - M);
    float w3 = m3.y * __builtin_amdgcn_exp2f(m3.x - M);
    float winv = 1.f / (w0 + w1 + w2 + w3);

    bf16x4 p0 = *(const bf16x4*)(Op01 + prow * 64 + dd);
    bf16x4 p1 = *(const bf16x4*)(Op01 + (SPLIT_ROWS + prow) * 64 + dd);
    bf16x4 p2 = *(const bf16x4*)(Op23 + prow * 64 + dd);
    bf16x4 p3 = *(const bf16x4*)(Op23 + (SPLIT_ROWS + prow) * 64 + dd);
    float4 rv = ((const float4*)resid)[row * 128 + tid];

    float x0 = (w0 * (float)p0[0] + w1 * (float)p1[0] + w2 * (float)p2[0] + w3 * (float)p3[0]) * winv + rv.x;
    float x1 = (w0 * (float)p0[1] + w1 * (float)p1[1] + w2 * (float)p2[1] + w3 * (float)p3[1]) * winv + rv.y;
    float x2 = (w0 * (float)p0[2] + w1 * (float)p1[2] + w2 * (float)p2[2] + w3 * (float)p3[2]) * winv + rv.z;
    float x3 = (w0 * (float)p0[3] + w1 * (float)p1[3] + w2 * (float)p2[3] + w3 * (float)p3[3]) * winv + rv.w;

    float s = x0 + x1 + x2 + x3;
    float sq = x0 * x0 + x1 * x1 + x2 * x2 + x3 * x3;
#pragma unroll
    for (int dl = 1; dl < 64; dl <<= 1) { s += __shfl_xor(s, dl); sq += __shfl_xor(sq, dl); }
    __shared__ float red[2][2];
    const int wid = tid >> 6;
    if ((tid & 63) == 0) { red[wid][0] = s; red[wid][1] = sq; }
    __syncthreads();
    s = red[0][0] + red[1][0];
    sq = red[0][1] + red[1][1];
    float mu = s * (1.f / 512.f);
    float var = sq * (1.f / 512.f) - mu * mu;
    float rstd = rsqrtf(var + 1e-5f);
    const float4 gv = ((const float4*)g)[tid];
    const float4 bv = ((const float4*)bta)[tid];
    bf16x4 o;
    o[0] = (bf16_t)((x0 - mu) * rstd * gv.x + bv.x);
    o[1] = (bf16_t)((x1 - mu) * rstd * gv.y + bv.y);
    o[2] = (bf16_t)((x2 - mu) * rstd * gv.z + bv.z);
    o[3] = (bf16_t)((x3 - mu) * rstd * gv.w + bv.w);
    *(bf16x4*)(outb + (size_t)row * 512 + tid * 4) = o;
}

// ---------------- fused residual-add + LayerNorm (D=512) ----------------
template<bool RESBF>
__global__ __launch_bounds__(128)
void add_ln_kernel(const float* __restrict__ a, const void* __restrict__ res,
                   const float* __restrict__ g, const float* __restrict__ bta,
                   float* outf, bf16_t* outb)
{
    const int row = blockIdx.x, tid = threadIdx.x;
    const float4* a4 = (const float4*)(a + (size_t)row * 512);
    float4 av = a4[tid];
    float r0, r1, r2, r3;
    if (RESBF) {
        bf16x4 rv = ((const bf16x4*)res)[row * 128 + tid];
        r0 = (float)rv[0]; r1 = (float)rv[1]; r2 = (float)rv[2]; r3 = (float)rv[3];
    } else {
        float4 rv = ((const float4*)res)[row * 128 + tid];
        r0 = rv.x; r1 = rv.y; r2 = rv.z; r3 = rv.w;
    }
    float x0 = av.x + r0, x1 = av.y + r1, x2 = av.z + r2, x3 = av.w + r3;
    float s = x0 + x1 + x2 + x3;
    float sq = x0 * x0 + x1 * x1 + x2 * x2 + x3 * x3;
#pragma unroll
    for (int d = 1; d < 64; d <<= 1) { s += __shfl_xor(s, d); sq += __shfl_xor(sq, d); }
    __shared__ float red[2][2];
    const int wid = tid >> 6;
    if ((tid & 63) == 0) { red[wid][0] = s; red[wid][1] = sq; }
    __syncthreads();
    s = red[0][0] + red[1][0];
    sq = red[0][1] + red[1][1];
    float mu = s * (1.f / 512.f);
    float var = sq * (1.f / 512.f) - mu * mu;
    float rstd = rsqrtf(var + 1e-5f);
    const float4* g4 = (const float4*)g;
    const float4* b4 = (const float4*)bta;
    float4 gv = g4[tid], bv = b4[tid];
    float4 y;
    y.x = (x0 - mu) * rstd * gv.x + bv.x;
    y.y = (x1 - mu) * rstd * gv.y + bv.y;
    y.z = (x2 - mu) * rstd * gv.z + bv.z;
    y.w = (x3 - mu) * rstd * gv.w + bv.w;
    if (outf) ((float4*)(outf + (size_t)row * 512))[tid] = y;
    if (outb) {
        bf16x4 o;
        o[0] = (bf16_t)y.x; o[1] = (bf16_t)y.y; o[2] = (bf16_t)y.z; o[3] = (bf16_t)y.w;
        *(bf16x4*)(outb + (size_t)row * 512 + tid * 4) = o;
    }
}

// ---------------- orchestration ----------------
// Workspace arena (29.5 MB high-water; lifetime-safe aliasing) — R13 layout (verified):
//   0- 2 MB : W1t    (A->F)
//   2- 4 MB : W2t    (A->G)
//   4-12 MB : Xb(4-8)+Eb(8-12) (A->B); then Op01 splits 0-1 (D->E); then Hb[0:8MB] (F->G)
//  12-24 MB : QKVb   (B->D); then Hb[8:16MB] at 12-20 (F->G); 20-24 free
//  24-28 MB : Vtb    (C->D); then out1b (E->H)   <-- disjoint from Op01/Op23
//  28-29.5  : Wqkvt  (A->B); then ml 1MB (4x32768 float2) (D->E)
// d_out: Op23 splits 2-3 (D->E); then FF f32 (G->H, in-place LN2).
extern "C" void kernel_launch(void* const* d_in, const int* in_sizes, int n_in,
                              void* d_out, int out_size, void* d_ws, size_t ws_size,
                              hipStream_t stream)
{
    const float* inputs = (const float*)d_in[0];
    const float* encx   = (const float*)d_in[1];
    const float* Wq     = (const float*)d_in[2];
    const float* Wk     = (const float*)d_in[3];
    const float* Wv     = (const float*)d_in[4];
    const float* ln1g   = (const float*)d_in[5];
    const float* ln1b   = (const float*)d_in[6];
    const float* W1     = (const float*)d_in[7];
    const float* b1     = (const float*)d_in[8];
    const float* W2     = (const float*)d_in[9];
    const float* b2     = (const float*)d_in[10];
    const float* ln2g   = (const float*)d_in[11];
    const float* ln2b   = (const float*)d_in[12];

    char* ws = (char*)d_ws;
    const size_t MB = 1u << 20;
    bf16_t* W1t   = (bf16_t*)(ws);
    bf16_t* W2t   = (bf16_t*)(ws + 2 * MB);
    bf16_t* Xb    = (bf16_t*)(ws + 4 * MB);
    bf16_t* Op01  = (bf16_t*)(ws + 4 * MB);       // 8 MB, aliases Xb+Eb (dead after QKV gemm)
    bf16_t* Hb    = (bf16_t*)(ws + 4 * MB);       // 16 MB @4-20, aliases Op01(dead after E)+QKVb
    bf16_t* Eb    = (bf16_t*)(ws + 8 * MB);
    bf16_t* QKVb  = (bf16_t*)(ws + 12 * MB);
    bf16_t* Vtb   = (bf16_t*)(ws + 24 * MB);
    bf16_t* out1b = (bf16_t*)(ws + 24 * MB);      // 4 MB, aliases Vtb (dead after flash)
    bf16_t* Wqkvt = (bf16_t*)(ws + 28 * MB);
    float2* mlbuf = (float2*)(ws + 28 * MB);      // 1 MB, aliases Wqkvt (dead after QKV gemm)
    bf16_t* Op23  = (bf16_t*)d_out;               // 8 MB, d_out unused until combine_ln
    float*  FF    = (float*)d_out;                // FF (G->H, consumed in-place by ln2)

    // A. merged convert (Q path folds 0.125*log2(e)) + merged weight transposes
    cvt_both_kernel<<<4096, 256, 0, stream>>>(inputs, Xb, 0.125f * 1.44269504f, encx, Eb);
    wtrans_all_kernel<<<2816, 256, 0, stream>>>(Wq, Wk, Wv, W1, W2, Wqkvt, W1t, W2t);
    // B. fused QKV projection: C[4096][1536]
    gemm_kernel<128, true, false, false, true><<<dim3(32, 12), 256, 0, stream>>>(
        Xb, Eb, 4, Wqkvt, nullptr, QKVb, 512, 1536);
    // C. V -> Vt[bh][64][2048]
    vtrans_kernel<<<dim3(32, 16), 256, 0, stream>>>(QKVb, Vtb);
    // D. flash attention (kv-split 4, 4-wave blocks — R13 proven) -> partials
    flash_kernel<<<dim3(16, 16, 4), 256, 0, stream>>>(QKVb, Vtb, Op01, Op23, mlbuf);
    // E. fused combine + LN1: out1 = LN(O + inputs) -> bf16 at 24-28 MB
    combine_ln_kernel<<<4096, 128, 0, stream>>>(Op01, Op23, mlbuf, inputs, ln1g, ln1b, out1b);
    // F. H = relu(out1 @ W1 + b1)  [4096][2048] bf16 -> 4-20 MB
    gemm_kernel<128, false, true, true, true><<<dim3(32, 16), 256, 0, stream>>>(
        out1b, nullptr, 0, W1t, b1, Hb, 512, 2048);
    // G. FF = H @ W2 + b2  [4096][512] f32 -> d_out
    gemm_kernel<64, false, true, false, false><<<dim3(64, 4), 256, 0, stream>>>(
        Hb, nullptr, 0, W2t, b2, FF, 2048, 512);
    // H. final = LN(FF + out1b) -> d_out (in-place, row-local)
    add_ln_kernel<true><<<4096, 128, 0, stream>>>(FF, out1b, ln2g, ln2b, (float*)d_out, nullptr);
}

// Round 16
// 123.703 us; speedup vs baseline: 1.1773x; 1.0735x over previous
//
#include <hip/hip_runtime.h>

typedef __bf16 bf16_t;
typedef __bf16 bf16x8 __attribute__((ext_vector_type(8)));
typedef __bf16 bf16x4 __attribute__((ext_vector_type(4)));
typedef float f32x4 __attribute__((ext_vector_type(4)));
typedef float f32x16 __attribute__((ext_vector_type(16)));
typedef unsigned int u32;
typedef unsigned int u32x2 __attribute__((ext_vector_type(2)));

#define GLB_AS(p) ((const __attribute__((address_space(1))) unsigned int*)(p))
#define LDS_AS(p) ((__attribute__((address_space(3))) unsigned int*)(p))

// rows per KV-split = 16 bh * 2048 q = 32768; 4 splits of 512 kv each
#define SPLIT_ROWS 32768
#define KLD 68   // K tile [32 kv][64 d] row stride (pad +4): ~0 conflicts (R9/R13-measured)
#define VLD 44   // V^T tile [64 d][32 kv] row stride (pad +12): ~0 conflicts (R9/R13-measured)

// ---------------- merged prep: fp32->bf16 converts (jobs 0-4095) + weight transposes (4096-6911) ----------------
__global__ void prep_kernel(const float* __restrict__ inputs, bf16_t* __restrict__ Xb, float scaleQ,
                            const float* __restrict__ encx, bf16_t* __restrict__ Eb,
                            const float* __restrict__ Wq, const float* __restrict__ Wk,
                            const float* __restrict__ Wv, const float* __restrict__ W1,
                            const float* __restrict__ W2, bf16_t* __restrict__ Wqkvt,
                            bf16_t* __restrict__ W1t, bf16_t* __restrict__ W2t)
{
    __shared__ float tile[32][33];
    const int bid = blockIdx.x;
    const int tid = threadIdx.x;
    if (bid < 4096) {
        const float* in;
        bf16_t* out;
        float scale;
        int i;
        if (bid < 2048) { in = inputs; out = Xb; scale = scaleQ; i = (bid * 256 + tid) * 4; }
        else            { in = encx;   out = Eb; scale = 1.0f;   i = ((bid - 2048) * 256 + tid) * 4; }
        float4 v = *(const float4*)(in + i);
        bf16x4 o;
        o[0] = (bf16_t)(v.x * scale); o[1] = (bf16_t)(v.y * scale);
        o[2] = (bf16_t)(v.z * scale); o[3] = (bf16_t)(v.w * scale);
        *(bf16x4*)(out + i) = o;
        return;
    }
    const int j = bid - 4096;
    const float* in;
    bf16_t* out;
    int R, C, bx, by;
    if (j < 768) {
        int k = j >> 8, l = j & 255;
        in = (k == 0) ? Wq : (k == 1) ? Wk : Wv;
        out = Wqkvt + k * 512 * 512;
        R = 512; C = 512; bx = l & 15; by = l >> 4;
    } else if (j < 1792) {
        int l = j - 768;
        in = W1; out = W1t; R = 512; C = 2048; bx = l % 64; by = l / 64;
    } else {
        int l = j - 1792;
        in = W2; out = W2t; R = 2048; C = 512; bx = l % 16; by = l / 16;
    }
    const int r0 = by * 32, c0 = bx * 32;
#pragma unroll
    for (int t = 0; t < 4; t++) {
        int r = t * 8 + (tid >> 5), c = tid & 31;
        tile[r][c] = in[(size_t)(r0 + r) * C + c0 + c];
    }
    __syncthreads();
#pragma unroll
    for (int t = 0; t < 4; t++) {
        int c = t * 8 + (tid >> 5), r = tid & 31;
        out[(size_t)(c0 + c) * R + r0 + r] = (bf16_t)tile[r][c];
    }
}

// ---------------- V transpose: QKV cols 1024..1535 -> Vt[bh][64][2048] ----------------
__global__ void vtrans_kernel(const bf16_t* __restrict__ qkv, bf16_t* __restrict__ vt)
{
    __shared__ bf16_t t[64][68];
    const int tid = threadIdx.x;
    const int lk0 = blockIdx.x * 64;
    const int bh = blockIdx.y, b = bh >> 3, h = bh & 7;
#pragma unroll
    for (int j = 0; j < 16; j++) {
        int e = j * 256 + tid;
        int lk_i = e >> 6, d = e & 63;
        t[lk_i][d] = qkv[(size_t)(b * 2048 + lk0 + lk_i) * 1536 + 1024 + h * 64 + d];
    }
    __syncthreads();
#pragma unroll
    for (int j = 0; j < 16; j++) {
        int e = j * 256 + tid;
        int d_i = e >> 6, lk = e & 63;
        vt[((size_t)bh * 64 + d_i) * 2048 + lk0 + lk] = t[lk][d_i];
    }
}

// ---------------- GEMM: C[M][N] = A[M][K] @ Bt[N][K]^T ----------------
// BM x BN tile, BK=32, 4 waves (2x2); 2-phase double-buffered LDS (T3-minimum).
template<int BM, int BN, bool SPLITA, bool BIAS, bool RELU, bool OUTBF16>
__global__ __launch_bounds__(256)
void gemm_kernel(const bf16_t* __restrict__ A0, const bf16_t* __restrict__ A1, int nsplit,
                 const bf16_t* __restrict__ Bt, const float* __restrict__ bias,
                 void* __restrict__ Cout, int K, int ldC)
{
    constexpr int FR = BM / 32, FC = BN / 32;
    __shared__ __align__(16) bf16_t As[2][BM * 32];
    __shared__ __align__(16) bf16_t Bs[2][BN * 32];
    const int bm = blockIdx.x, bn = blockIdx.y;
    const bf16_t* A = (!SPLITA || bn < nsplit) ? A0 : A1;
    const int tid = threadIdx.x;
    const int lane = tid & 63;
    const int wid = tid >> 6;
    const int wr = wid >> 1, wc = wid & 1;

    f32x4 acc[FR][FC] = {};

    const int cb = wid * 2;
    // B staging: BN==128 -> 2 chunks/wave; BN==64 -> 1 chunk/wave
    const int lbB0 = (BN == 128 ? cb * 1024 : wid * 1024) + lane * 16;
    const int rowB0 = lbB0 >> 6, colB0 = (lbB0 & 63) >> 1;
    const int rowB1 = (lbB0 + 1024) >> 6, colB1 = ((lbB0 + 1024) & 63) >> 1;
    // A staging: BM==128 -> 2 chunks/wave; BM==64 -> 1 chunk/wave
    const int lbA0 = (BM == 128 ? cb * 1024 : wid * 1024) + lane * 16;
    const int rowA0 = lbA0 >> 6, colA0 = (lbA0 & 63) >> 1;
    const int rowA1 = (lbA0 + 1024) >> 6, colA1 = ((lbA0 + 1024) & 63) >> 1;

    const bf16_t* Abase = A + (size_t)(bm * BM) * K;
    const bf16_t* Bbase = Bt + (size_t)(bn * BN) * K;

    auto stage = [&](int k0, int b_) {
        if constexpr (BM == 128) {
            __builtin_amdgcn_global_load_lds(GLB_AS(Abase + (size_t)rowA0 * K + k0 + colA0), LDS_AS(&As[b_][cb * 512]), 16, 0, 0);
            __builtin_amdgcn_global_load_lds(GLB_AS(Abase + (size_t)rowA1 * K + k0 + colA1), LDS_AS(&As[b_][cb * 512 + 512]), 16, 0, 0);
        } else {
            __builtin_amdgcn_global_load_lds(GLB_AS(Abase + (size_t)rowA0 * K + k0 + colA0), LDS_AS(&As[b_][wid * 512]), 16, 0, 0);
        }
        if constexpr (BN == 128) {
            __builtin_amdgcn_global_load_lds(GLB_AS(Bbase + (size_t)rowB0 * K + k0 + colB0), LDS_AS(&Bs[b_][cb * 512]), 16, 0, 0);
            __builtin_amdgcn_global_load_lds(GLB_AS(Bbase + (size_t)rowB1 * K + k0 + colB1), LDS_AS(&Bs[b_][cb * 512 + 512]), 16, 0, 0);
        } else {
            __builtin_amdgcn_global_load_lds(GLB_AS(Bbase + (size_t)rowB0 * K + k0 + colB0), LDS_AS(&Bs[b_][wid * 512]), 16, 0, 0);
        }
    };

    stage(0, 0);
    __syncthreads();

    int cur = 0;
    for (int k0 = 0; k0 < K; k0 += 32) {
        if (k0 + 32 < K) stage(k0 + 32, cur ^ 1);

        bf16x8 af[FR], bfr[FC];
#pragma unroll
        for (int f = 0; f < FR; f++)
            af[f] = *(const bf16x8*)&As[cur][(wr * (BM / 2) + f * 16 + (lane & 15)) * 32 + (lane >> 4) * 8];
#pragma unroll
        for (int f = 0; f < FC; f++)
            bfr[f] = *(const bf16x8*)&Bs[cur][(wc * (BN / 2) + f * 16 + (lane & 15)) * 32 + (lane >> 4) * 8];
#pragma unroll
        for (int fr = 0; fr < FR; fr++)
#pragma unroll
            for (int fc = 0; fc < FC; fc++)
                acc[fr][fc] = __builtin_amdgcn_mfma_f32_16x16x32_bf16(af[fr], bfr[fc], acc[fr][fc], 0, 0, 0);

        __syncthreads();
        cur ^= 1;
    }

    const int rg = (lane >> 4) * 4, cl = lane & 15;
#pragma unroll
    for (int fc = 0; fc < FC; fc++) {
        const int col = bn * BN + wc * (BN / 2) + fc * 16 + cl;
        float bv = 0.f;
        if (BIAS) bv = bias[col];
#pragma unroll
        for (int fr = 0; fr < FR; fr++) {
#pragma unroll
            for (int r = 0; r < 4; r++) {
                int rowg = bm * BM + wr * (BM / 2) + fr * 16 + rg + r;
                float v = acc[fr][fc][r] + bv;
                if (RELU) v = fmaxf(v, 0.f);
                if (OUTBF16) ((bf16_t*)Cout)[(size_t)rowg * ldC + col] = (bf16_t)v;
                else         ((float*)Cout)[(size_t)rowg * ldC + col] = v;
            }
        }
    }
}

// ---------------- flash attention: swapped-QK^T 32x32, block-shared LDS (R13, proven) ----------------
union BU { bf16x8 v; u32 d[4]; };

static __device__ __forceinline__ u32 pkbf(float a, float b)
{
    union { bf16_t h[2]; u32 w; } u;
    u.h[0] = (bf16_t)a; u.h[1] = (bf16_t)b;
    return u.w;
}

// permlane32_swap: x = {a.lo_lanes, b.lo_lanes}, y = {a.hi_lanes, b.hi_lanes}
static __device__ __forceinline__ void plswap(u32 a, u32 b, u32& x, u32& y)
{
#if __has_builtin(__builtin_amdgcn_permlane32_swap)
    u32x2 r = __builtin_amdgcn_permlane32_swap(a, b, false, false);
    x = r[0]; y = r[1];
#else
    const bool hi = (threadIdx.x & 32) != 0;
    u32 sb = __shfl_xor(b, 32), sa = __shfl_xor(a, 32);
    x = hi ? sb : a;
    y = hi ? b : sa;
#endif
}

// grid (16 qblocks, 16 bh, 4 kv-splits); 4 waves x 32 q-rows = 128 q/block; KVBLK=32.
// R13 verbatim (43 µs measured).
__global__ __launch_bounds__(256)
void flash_kernel(const bf16_t* __restrict__ QKV, const bf16_t* __restrict__ Vt,
                  bf16_t* __restrict__ Op01, bf16_t* __restrict__ Op23,
                  float2* __restrict__ ml)
{
    const int tid = threadIdx.x, lane = tid & 63, wid = tid >> 6;
    const int bh = blockIdx.y, b = bh >> 3, h = bh & 7;
    const int split = blockIdx.z;
    const int qbase = blockIdx.x * 128 + wid * 32;
    const int l31 = lane & 31, hi = lane >> 5;

    __shared__ __align__(16) bf16_t Kst[2][32 * KLD];
    __shared__ __align__(16) bf16_t Vst[2][64 * VLD];
    __shared__ __align__(16) bf16_t tlds[4][32 * 68];
    bf16_t* tw = &tlds[wid][0];

    const bf16_t* Qp = QKV + (size_t)(b * 2048 + qbase + l31) * 1536 + h * 64 + hi * 8;
    const bf16_t* Kbase = QKV + (size_t)(b * 2048) * 1536 + 512 + h * 64;
    const bf16_t* Vbase = Vt + (size_t)bh * 64 * 2048;

    const int kr = tid >> 3, kc = (tid & 7) * 8;
    const int vr = tid >> 2, vc = (tid & 3) * 8;

    bf16x8 qf[4];
#pragma unroll
    for (int t = 0; t < 4; t++)
        qf[t] = *(const bf16x8*)(Qp + t * 16);

    bf16x8 ones;
#pragma unroll
    for (int e = 0; e < 8; e++) ones[e] = (bf16_t)1.0f;

    f32x16 acc0 = {}, acc1 = {}, accS = {};
    float mrun = -1e30f;

    const int kv0 = split * 512;

    bf16x8 kreg = *(const bf16x8*)(Kbase + (size_t)(kv0 + kr) * 1536 + kc);
    bf16x8 vreg = *(const bf16x8*)(Vbase + (size_t)vr * 2048 + kv0 + vc);
    *(bf16x8*)&Kst[0][kr * KLD + kc] = kreg;
    *(bf16x8*)&Vst[0][vr * VLD + vc] = vreg;
    __syncthreads();

    int buf = 0;
#pragma unroll 2
    for (int kt = kv0; kt < kv0 + 512; kt += 32) {
        const bool nxt = (kt + 32 < kv0 + 512);
        if (nxt) {
            kreg = *(const bf16x8*)(Kbase + (size_t)(kt + 32 + kr) * 1536 + kc);
            vreg = *(const bf16x8*)(Vbase + (size_t)vr * 2048 + kt + 32 + vc);
        }

        bf16x8 kf[4];
#pragma unroll
        for (int t = 0; t < 4; t++)
            kf[t] = *(const bf16x8*)&Kst[buf][l31 * KLD + hi * 8 + t * 16];
        bf16x8 vf00 = *(const bf16x8*)&Vst[buf][l31 * VLD + hi * 8];
        bf16x8 vf01 = *(const bf16x8*)&Vst[buf][l31 * VLD + 16 + hi * 8];
        bf16x8 vf10 = *(const bf16x8*)&Vst[buf][(32 + l31) * VLD + hi * 8];
        bf16x8 vf11 = *(const bf16x8*)&Vst[buf][(32 + l31) * VLD + 16 + hi * 8];

        f32x16 p = {};
        __builtin_amdgcn_s_setprio(1);
        p = __builtin_amdgcn_mfma_f32_32x32x16_bf16(kf[0], qf[0], p, 0, 0, 0);
        p = __builtin_amdgcn_mfma_f32_32x32x16_bf16(kf[1], qf[1], p, 0, 0, 0);
        p = __builtin_amdgcn_mfma_f32_32x32x16_bf16(kf[2], qf[2], p, 0, 0, 0);
        p = __builtin_amdgcn_mfma_f32_32x32x16_bf16(kf[3], qf[3], p, 0, 0, 0);
        __builtin_amdgcn_s_setprio(0);

        float x0 = fmaxf(p[0], p[8]),  x1 = fmaxf(p[1], p[9]);
        float x2 = fmaxf(p[2], p[10]), x3 = fmaxf(p[3], p[11]);
        float x4 = fmaxf(p[4], p[12]), x5 = fmaxf(p[5], p[13]);
        float x6 = fmaxf(p[6], p[14]), x7 = fmaxf(p[7], p[15]);
        x0 = fmaxf(x0, x4); x1 = fmaxf(x1, x5); x2 = fmaxf(x2, x6); x3 = fmaxf(x3, x7);
        float cm = fmaxf(fmaxf(x0, x1), fmaxf(x2, x3));
        {
            u32 r0, r1;
            plswap(__float_as_uint(cm), __float_as_uint(cm), r0, r1);
            cm = fmaxf(__uint_as_float(r0), __uint_as_float(r1));
        }

        if (__any(cm > mrun + 12.0f)) {
            float mnew = fmaxf(mrun, cm);
            float fac = __builtin_amdgcn_exp2f(mrun - mnew);
#pragma unroll
            for (int i = 0; i < 16; i++) { acc0[i] *= fac; acc1[i] *= fac; accS[i] *= fac; }
            mrun = mnew;
        }

        float e[16];
#pragma unroll
        for (int i = 0; i < 16; i++) e[i] = __builtin_amdgcn_exp2f(p[i] - mrun);

        u32 pk0 = pkbf(e[0], e[1]),   pk1 = pkbf(e[2], e[3]);
        u32 pk2 = pkbf(e[4], e[5]),   pk3 = pkbf(e[6], e[7]);
        u32 pk4 = pkbf(e[8], e[9]),   pk5 = pkbf(e[10], e[11]);
        u32 pk6 = pkbf(e[12], e[13]), pk7 = pkbf(e[14], e[15]);
        BU b0, b1;
        plswap(pk0, pk2, b0.d[0], b0.d[2]);
        plswap(pk1, pk3, b0.d[1], b0.d[3]);
        plswap(pk4, pk6, b1.d[0], b1.d[2]);
        plswap(pk5, pk7, b1.d[1], b1.d[3]);

        __builtin_amdgcn_s_setprio(1);
        acc0 = __builtin_amdgcn_mfma_f32_32x32x16_bf16(vf00, b0.v, acc0, 0, 0, 0);
        acc0 = __builtin_amdgcn_mfma_f32_32x32x16_bf16(vf01, b1.v, acc0, 0, 0, 0);
        acc1 = __builtin_amdgcn_mfma_f32_32x32x16_bf16(vf10, b0.v, acc1, 0, 0, 0);
        acc1 = __builtin_amdgcn_mfma_f32_32x32x16_bf16(vf11, b1.v, acc1, 0, 0, 0);
        accS = __builtin_amdgcn_mfma_f32_32x32x16_bf16(ones, b0.v, accS, 0, 0, 0);
        accS = __builtin_amdgcn_mfma_f32_32x32x16_bf16(ones, b1.v, accS, 0, 0, 0);
        __builtin_amdgcn_s_setprio(0);

        if (nxt) {
            *(bf16x8*)&Kst[buf ^ 1][kr * KLD + kc] = kreg;
            *(bf16x8*)&Vst[buf ^ 1][vr * VLD + vc] = vreg;
        }
        __syncthreads();
        buf ^= 1;
    }

    const float lsum = accS[0];
    float inv = 1.f / lsum;
#pragma unroll
    for (int r = 0; r < 16; r++) {
        int drow = (r & 3) + 8 * (r >> 2) + 4 * hi;
        tw[l31 * 68 + drow]      = (bf16_t)(acc0[r] * inv);
        tw[l31 * 68 + 32 + drow] = (bf16_t)(acc1[r] * inv);
    }
    bf16_t* Op = (split < 2) ? Op01 + (size_t)split * SPLIT_ROWS * 64
                             : Op23 + (size_t)(split - 2) * SPLIT_ROWS * 64;
    const size_t rowbase = (size_t)bh * 2048 + qbase;
#pragma unroll
    for (int ps = 0; ps < 4; ps++) {
        int rr = (lane >> 3) + ps * 8;
        int cc = lane & 7;
        bf16x8 ov = *(const bf16x8*)&tw[rr * 68 + cc * 8];
        *(bf16x8*)(Op + (rowbase + rr) * 64 + cc * 8) = ov;
    }
    if (lane < 32)
        ml[(size_t)split * SPLIT_ROWS + rowbase + l31] = make_float2(mrun, lsum);
}

// ---------------- fused combine(4 splits) + residual-add + LayerNorm -> out1b bf16 ----------------
// NOTE: outb must NOT alias Op01/Op23 (R12 lesson: cross-block read/write race).
__global__ __launch_bounds__(128)
void combine_ln_kernel(const bf16_t* __restrict__ Op01, const bf16_t* __restrict__ Op23,
                       const float2* __restrict__ ml, const float* __restrict__ resid,
                       const float* __restrict__ g, const float* __restrict__ bta,
                       bf16_t* __restrict__ outb)
{
    const int row = blockIdx.x;            // b*2048 + q
    const int tid = threadIdx.x;
    const int b = row >> 11, q = row & 2047;
    const int d = tid * 4, h = d >> 6, dd = d & 63;
    const size_t prow = ((size_t)(b * 8 + h)) * 2048 + q;

    float2 m0 = ml[prow];
    float2 m1 = ml[SPLIT_ROWS + prow];
    float2 m2 = ml[2 * SPLIT_ROWS + prow];
    float2 m3 = ml[3 * SPLIT_ROWS + prow];
    float M = fmaxf(fmaxf(m0.x, m1.x), fmaxf(m2.x, m3.x));
    float w0 = m0.y * __builtin_amdgcn_exp2f(m0.x - M);
    float w1 = m1.y * __builtin_amdgcn_exp2f(m1.x - M);
    float w2 = m2.y * __builtin_amdgcn_exp2f(m2.x - M);
    float w3 = m3.y * __builtin_amdgcn_exp2f(m3.x - M);
    float winv = 1.f / (w0 + w1 + w2 + w3);

    bf16x4 p0 = *(const bf16x4*)(Op01 + prow * 64 + dd);
    bf16x4 p1 = *(const bf16x4*)(Op01 + (SPLIT_ROWS + prow) * 64 + dd);
    bf16x4 p2 = *(const bf16x4*)(Op23 + prow * 64 + dd);
    bf16x4 p3 = *(const bf16x4*)(Op23 + (SPLIT_ROWS + prow) * 64 + dd);
    float4 rv = ((const float4*)resid)[row * 128 + tid];

    float x0 = (w0 * (float)p0[0] + w1 * (float)p1[0] + w2 * (float)p2[0] + w3 * (float)p3[0]) * winv + rv.x;
    float x1 = (w0 * (float)p0[1] + w1 * (float)p1[1] + w2 * (float)p2[1] + w3 * (float)p3[1]) * winv + rv.y;
    float x2 = (w0 * (float)p0[2] + w1 * (float)p1[2] + w2 * (float)p2[2] + w3 * (float)p3[2]) * winv + rv.z;
    float x3 = (w0 * (float)p0[3] + w1 * (float)p1[3] + w2 * (float)p2[3] + w3 * (float)p3[3]) * winv + rv.w;

    float s = x0 + x1 + x2 + x3;
    float sq = x0 * x0 + x1 * x1 + x2 * x2 + x3 * x3;
#pragma unroll
    for (int dl = 1; dl < 64; dl <<= 1) { s += __shfl_xor(s, dl); sq += __shfl_xor(sq, dl); }
    __shared__ float red[2][2];
    const int wid = tid >> 6;
    if ((tid & 63) == 0) { red[wid][0] = s; red[wid][1] = sq; }
    __syncthreads();
    s = red[0][0] + red[1][0];
    sq = red[0][1] + red[1][1];
    float mu = s * (1.f / 512.f);
    float var = sq * (1.f / 512.f) - mu * mu;
    float rstd = rsqrtf(var + 1e-5f);
    const float4 gv = ((const float4*)g)[tid];
    const float4 bv = ((const float4*)bta)[tid];
    bf16x4 o;
    o[0] = (bf16_t)((x0 - mu) * rstd * gv.x + bv.x);
    o[1] = (bf16_t)((x1 - mu) * rstd * gv.y + bv.y);
    o[2] = (bf16_t)((x2 - mu) * rstd * gv.z + bv.z);
    o[3] = (bf16_t)((x3 - mu) * rstd * gv.w + bv.w);
    *(bf16x4*)(outb + (size_t)row * 512 + tid * 4) = o;
}

// ---------------- fused residual-add + LayerNorm (D=512) ----------------
template<bool RESBF>
__global__ __launch_bounds__(128)
void add_ln_kernel(const float* __restrict__ a, const void* __restrict__ res,
                   const float* __restrict__ g, const float* __restrict__ bta,
                   float* outf, bf16_t* outb)
{
    const int row = blockIdx.x, tid = threadIdx.x;
    const float4* a4 = (const float4*)(a + (size_t)row * 512);
    float4 av = a4[tid];
    float r0, r1, r2, r3;
    if (RESBF) {
        bf16x4 rv = ((const bf16x4*)res)[row * 128 + tid];
        r0 = (float)rv[0]; r1 = (float)rv[1]; r2 = (float)rv[2]; r3 = (float)rv[3];
    } else {
        float4 rv = ((const float4*)res)[row * 128 + tid];
        r0 = rv.x; r1 = rv.y; r2 = rv.z; r3 = rv.w;
    }
    float x0 = av.x + r0, x1 = av.y + r1, x2 = av.z + r2, x3 = av.w + r3;
    float s = x0 + x1 + x2 + x3;
    float sq = x0 * x0 + x1 * x1 + x2 * x2 + x3 * x3;
#pragma unroll
    for (int d = 1; d < 64; d <<= 1) { s += __shfl_xor(s, d); sq += __shfl_xor(sq, d); }
    __shared__ float red[2][2];
    const int wid = tid >> 6;
    if ((tid & 63) == 0) { red[wid][0] = s; red[wid][1] = sq; }
    __syncthreads();
    s = red[0][0] + red[1][0];
    sq = red[0][1] + red[1][1];
    float mu = s * (1.f / 512.f);
    float var = sq * (1.f / 512.f) - mu * mu;
    float rstd = rsqrtf(var + 1e-5f);
    const float4* g4 = (const float4*)g;
    const float4* b4 = (const float4*)bta;
    float4 gv = g4[tid], bv = b4[tid];
    float4 y;
    y.x = (x0 - mu) * rstd * gv.x + bv.x;
    y.y = (x1 - mu) * rstd * gv.y + bv.y;
    y.z = (x2 - mu) * rstd * gv.z + bv.z;
    y.w = (x3 - mu) * rstd * gv.w + bv.w;
    if (outf) ((float4*)(outf + (size_t)row * 512))[tid] = y;
    if (outb) {
        bf16x4 o;
        o[0] = (bf16_t)y.x; o[1] = (bf16_t)y.y; o[2] = (bf16_t)y.z; o[3] = (bf16_t)y.w;
        *(bf16x4*)(outb + (size_t)row * 512 + tid * 4) = o;
    }
}

// ---------------- orchestration ----------------
// Workspace arena (29.5 MB high-water; lifetime-safe aliasing) — R13/R15 layout (verified):
//   0- 2 MB : W1t    (A->F)
//   2- 4 MB : W2t    (A->G)
//   4-12 MB : Xb(4-8)+Eb(8-12) (A->B); then Op01 splits 0-1 (D->E); then Hb[0:8MB] (F->G)
//  12-24 MB : QKVb   (B->D); then Hb[8:16MB] at 12-20 (F->G); 20-24 free
//  24-28 MB : Vtb    (C->D); then out1b (E->H)   <-- disjoint from Op01/Op23
//  28-29.5  : Wqkvt  (A->B); then ml 1MB (4x32768 float2) (D->E)
// d_out: Op23 splits 2-3 (D->E); then FF f32 (G->H, in-place LN2).
extern "C" void kernel_launch(void* const* d_in, const int* in_sizes, int n_in,
                              void* d_out, int out_size, void* d_ws, size_t ws_size,
                              hipStream_t stream)
{
    const float* inputs = (const float*)d_in[0];
    const float* encx   = (const float*)d_in[1];
    const float* Wq     = (const float*)d_in[2];
    const float* Wk     = (const float*)d_in[3];
    const float* Wv     = (const float*)d_in[4];
    const float* ln1g   = (const float*)d_in[5];
    const float* ln1b   = (const float*)d_in[6];
    const float* W1     = (const float*)d_in[7];
    const float* b1     = (const float*)d_in[8];
    const float* W2     = (const float*)d_in[9];
    const float* b2     = (const float*)d_in[10];
    const float* ln2g   = (const float*)d_in[11];
    const float* ln2b   = (const float*)d_in[12];

    char* ws = (char*)d_ws;
    const size_t MB = 1u << 20;
    bf16_t* W1t   = (bf16_t*)(ws);
    bf16_t* W2t   = (bf16_t*)(ws + 2 * MB);
    bf16_t* Xb    = (bf16_t*)(ws + 4 * MB);
    bf16_t* Op01  = (bf16_t*)(ws + 4 * MB);       // 8 MB, aliases Xb+Eb (dead after QKV gemm)
    bf16_t* Hb    = (bf16_t*)(ws + 4 * MB);       // 16 MB @4-20, aliases Op01(dead after E)+QKVb
    bf16_t* Eb    = (bf16_t*)(ws + 8 * MB);
    bf16_t* QKVb  = (bf16_t*)(ws + 12 * MB);
    bf16_t* Vtb   = (bf16_t*)(ws + 24 * MB);
    bf16_t* out1b = (bf16_t*)(ws + 24 * MB);      // 4 MB, aliases Vtb (dead after flash)
    bf16_t* Wqkvt = (bf16_t*)(ws + 28 * MB);
    float2* mlbuf = (float2*)(ws + 28 * MB);      // 1 MB, aliases Wqkvt (dead after QKV gemm)
    bf16_t* Op23  = (bf16_t*)d_out;               // 8 MB, d_out unused until combine_ln
    float*  FF    = (float*)d_out;                // FF (G->H, consumed in-place by ln2)

    // A. merged prep: converts (Q folds 0.125*log2 e) + weight transposes, one dispatch
    prep_kernel<<<6912, 256, 0, stream>>>(inputs, Xb, 0.125f * 1.44269504f, encx, Eb,
                                          Wq, Wk, Wv, W1, W2, Wqkvt, W1t, W2t);
    // B. fused QKV projection: C[4096][1536]; BM=64 -> 768 blocks = 3.0/CU exact
    gemm_kernel<64, 128, true, false, false, true><<<dim3(64, 12), 256, 0, stream>>>(
        Xb, Eb, 4, Wqkvt, nullptr, QKVb, 512, 1536);
    // C. V -> Vt[bh][64][2048]
    vtrans_kernel<<<dim3(32, 16), 256, 0, stream>>>(QKVb, Vtb);
    // D. flash attention (kv-split 4, 4-wave blocks — R13 proven) -> partials
    flash_kernel<<<dim3(16, 16, 4), 256, 0, stream>>>(QKVb, Vtb, Op01, Op23, mlbuf);
    // E. fused combine + LN1: out1 = LN(O + inputs) -> bf16 at 24-28 MB
    combine_ln_kernel<<<4096, 128, 0, stream>>>(Op01, Op23, mlbuf, inputs, ln1g, ln1b, out1b);
    // F. H = relu(out1 @ W1 + b1)  [4096][2048]; BM=128,BN=128 -> 512 blocks = 2.0/CU exact
    gemm_kernel<128, 128, false, true, true, true><<<dim3(32, 16), 256, 0, stream>>>(
        out1b, nullptr, 0, W1t, b1, Hb, 512, 2048);
    // G. FF = H @ W2 + b2  [4096][512]; BM=64,BN=64 -> 512 blocks = 2.0/CU exact
    gemm_kernel<64, 64, false, true, false, false><<<dim3(64, 8), 256, 0, stream>>>(
        Hb, nullptr, 0, W2t, b2, FF, 2048, 512);
    // H. final = LN(FF + out1b) -> d_out (in-place, row-local)
    add_ln_kernel<true><<<4096, 128, 0, stream>>>(FF, out1b, ln2g, ln2b, (float*)d_out, nullptr);
}

// Round 17
// 121.043 us; speedup vs baseline: 1.2031x; 1.0220x over previous
//
#include <hip/hip_runtime.h>

typedef __bf16 bf16_t;
typedef __bf16 bf16x8 __attribute__((ext_vector_type(8)));
typedef __bf16 bf16x4 __attribute__((ext_vector_type(4)));
typedef float f32x4 __attribute__((ext_vector_type(4)));
typedef float f32x16 __attribute__((ext_vector_type(16)));
typedef unsigned int u32;
typedef unsigned int u32x2 __attribute__((ext_vector_type(2)));

#define GLB_AS(p) ((const __attribute__((address_space(1))) unsigned int*)(p))
#define LDS_AS(p) ((__attribute__((address_space(3))) unsigned int*)(p))

// rows per KV-split = 16 bh * 2048 q = 32768; 4 splits of 512 kv each
#define SPLIT_ROWS 32768
#define KLD 68   // K tile [32 kv][64 d] row stride (pad +4): ~0 conflicts (R9/R13-measured)
#define VLD 44   // V^T tile [64 d][32 kv] row stride (pad +12): ~0 conflicts (R9/R13-measured)

// ---------------- merged prep: fp32->bf16 converts (jobs 0-4095) + weight transposes (4096-6911) ----------------
__global__ void prep_kernel(const float* __restrict__ inputs, bf16_t* __restrict__ Xb, float scaleQ,
                            const float* __restrict__ encx, bf16_t* __restrict__ Eb,
                            const float* __restrict__ Wq, const float* __restrict__ Wk,
                            const float* __restrict__ Wv, const float* __restrict__ W1,
                            const float* __restrict__ W2, bf16_t* __restrict__ Wqkvt,
                            bf16_t* __restrict__ W1t, bf16_t* __restrict__ W2t)
{
    __shared__ float tile[32][33];
    const int bid = blockIdx.x;
    const int tid = threadIdx.x;
    if (bid < 4096) {
        const float* in;
        bf16_t* out;
        float scale;
        int i;
        if (bid < 2048) { in = inputs; out = Xb; scale = scaleQ; i = (bid * 256 + tid) * 4; }
        else            { in = encx;   out = Eb; scale = 1.0f;   i = ((bid - 2048) * 256 + tid) * 4; }
        float4 v = *(const float4*)(in + i);
        bf16x4 o;
        o[0] = (bf16_t)(v.x * scale); o[1] = (bf16_t)(v.y * scale);
        o[2] = (bf16_t)(v.z * scale); o[3] = (bf16_t)(v.w * scale);
        *(bf16x4*)(out + i) = o;
        return;
    }
    const int j = bid - 4096;
    const float* in;
    bf16_t* out;
    int R, C, bx, by;
    if (j < 768) {
        int k = j >> 8, l = j & 255;
        in = (k == 0) ? Wq : (k == 1) ? Wk : Wv;
        out = Wqkvt + k * 512 * 512;
        R = 512; C = 512; bx = l & 15; by = l >> 4;
    } else if (j < 1792) {
        int l = j - 768;
        in = W1; out = W1t; R = 512; C = 2048; bx = l % 64; by = l / 64;
    } else {
        int l = j - 1792;
        in = W2; out = W2t; R = 2048; C = 512; bx = l % 16; by = l / 16;
    }
    const int r0 = by * 32, c0 = bx * 32;
#pragma unroll
    for (int t = 0; t < 4; t++) {
        int r = t * 8 + (tid >> 5), c = tid & 31;
        tile[r][c] = in[(size_t)(r0 + r) * C + c0 + c];
    }
    __syncthreads();
#pragma unroll
    for (int t = 0; t < 4; t++) {
        int c = t * 8 + (tid >> 5), r = tid & 31;
        out[(size_t)(c0 + c) * R + r0 + r] = (bf16_t)tile[r][c];
    }
}

// ---------------- GEMM: C[M][N] = A[M][K] @ Bt[N][K]^T ----------------
// BM x BN tile, BK=32, 4 waves (2x2); 2-phase double-buffered LDS.
// VFUSE (QKV only, BM=64): bn 0-3 -> Q cols (A=X), 4-7 -> K cols, 8-11 -> V cols written
// DIRECTLY transposed to Vt[bh][64][2048] (4 consecutive r = 4 consecutive lk = 8B store).
template<int BM, int BN, bool SPLITA, bool VFUSE, bool BIAS, bool RELU, bool OUTBF16>
__global__ __launch_bounds__(256)
void gemm_kernel(const bf16_t* __restrict__ A0, const bf16_t* __restrict__ A1, int nsplit,
                 const bf16_t* __restrict__ Bt, const float* __restrict__ bias,
                 void* __restrict__ Cout, bf16_t* __restrict__ VtOut, int K, int ldC)
{
    constexpr int FR = BM / 32, FC = BN / 32;
    __shared__ __align__(16) bf16_t As[2][BM * 32];
    __shared__ __align__(16) bf16_t Bs[2][BN * 32];
    const int bm = blockIdx.x, bn = blockIdx.y;
    const bf16_t* A = (!SPLITA || bn < nsplit) ? A0 : A1;
    const int tid = threadIdx.x;
    const int lane = tid & 63;
    const int wid = tid >> 6;
    const int wr = wid >> 1, wc = wid & 1;

    f32x4 acc[FR][FC] = {};

    const int cb = wid * 2;
    const int lbB0 = (BN == 128 ? cb * 1024 : wid * 1024) + lane * 16;
    const int rowB0 = lbB0 >> 6, colB0 = (lbB0 & 63) >> 1;
    const int rowB1 = (lbB0 + 1024) >> 6, colB1 = ((lbB0 + 1024) & 63) >> 1;
    const int lbA0 = (BM == 128 ? cb * 1024 : wid * 1024) + lane * 16;
    const int rowA0 = lbA0 >> 6, colA0 = (lbA0 & 63) >> 1;
    const int rowA1 = (lbA0 + 1024) >> 6, colA1 = ((lbA0 + 1024) & 63) >> 1;

    const bf16_t* Abase = A + (size_t)(bm * BM) * K;
    const bf16_t* Bbase = Bt + (size_t)(bn * BN) * K;

    auto stage = [&](int k0, int b_) {
        if constexpr (BM == 128) {
            __builtin_amdgcn_global_load_lds(GLB_AS(Abase + (size_t)rowA0 * K + k0 + colA0), LDS_AS(&As[b_][cb * 512]), 16, 0, 0);
            __builtin_amdgcn_global_load_lds(GLB_AS(Abase + (size_t)rowA1 * K + k0 + colA1), LDS_AS(&As[b_][cb * 512 + 512]), 16, 0, 0);
        } else {
            __builtin_amdgcn_global_load_lds(GLB_AS(Abase + (size_t)rowA0 * K + k0 + colA0), LDS_AS(&As[b_][wid * 512]), 16, 0, 0);
        }
        if constexpr (BN == 128) {
            __builtin_amdgcn_global_load_lds(GLB_AS(Bbase + (size_t)rowB0 * K + k0 + colB0), LDS_AS(&Bs[b_][cb * 512]), 16, 0, 0);
            __builtin_amdgcn_global_load_lds(GLB_AS(Bbase + (size_t)rowB1 * K + k0 + colB1), LDS_AS(&Bs[b_][cb * 512 + 512]), 16, 0, 0);
        } else {
            __builtin_amdgcn_global_load_lds(GLB_AS(Bbase + (size_t)rowB0 * K + k0 + colB0), LDS_AS(&Bs[b_][wid * 512]), 16, 0, 0);
        }
    };

    stage(0, 0);
    __syncthreads();

    int cur = 0;
    for (int k0 = 0; k0 < K; k0 += 32) {
        if (k0 + 32 < K) stage(k0 + 32, cur ^ 1);

        bf16x8 af[FR], bfr[FC];
#pragma unroll
        for (int f = 0; f < FR; f++)
            af[f] = *(const bf16x8*)&As[cur][(wr * (BM / 2) + f * 16 + (lane & 15)) * 32 + (lane >> 4) * 8];
#pragma unroll
        for (int f = 0; f < FC; f++)
            bfr[f] = *(const bf16x8*)&Bs[cur][(wc * (BN / 2) + f * 16 + (lane & 15)) * 32 + (lane >> 4) * 8];
#pragma unroll
        for (int fr = 0; fr < FR; fr++)
#pragma unroll
            for (int fc = 0; fc < FC; fc++)
                acc[fr][fc] = __builtin_amdgcn_mfma_f32_16x16x32_bf16(af[fr], bfr[fc], acc[fr][fc], 0, 0, 0);

        __syncthreads();
        cur ^= 1;
    }

    const int rg = (lane >> 4) * 4, cl = lane & 15;
    if (VFUSE && bn >= 8) {
        // V block: write transposed to Vt[bh][64][2048]
#pragma unroll
        for (int fc = 0; fc < FC; fc++) {
            const int colv = (bn - 8) * BN + wc * (BN / 2) + fc * 16 + cl;  // 0-511
            const int h = colv >> 6, d = colv & 63;
#pragma unroll
            for (int fr = 0; fr < FR; fr++) {
                const int rowg = bm * BM + wr * (BM / 2) + fr * 16 + rg;    // base of 4
                const int b = rowg >> 11, lk = rowg & 2047;
                bf16x4 o;
#pragma unroll
                for (int r = 0; r < 4; r++) o[r] = (bf16_t)acc[fr][fc][r];
                *(bf16x4*)(VtOut + ((size_t)(b * 8 + h) * 64 + d) * 2048 + lk) = o;
            }
        }
        return;
    }
#pragma unroll
    for (int fc = 0; fc < FC; fc++) {
        const int col = bn * BN + wc * (BN / 2) + fc * 16 + cl;
        float bv = 0.f;
        if (BIAS) bv = bias[col];
#pragma unroll
        for (int fr = 0; fr < FR; fr++) {
#pragma unroll
            for (int r = 0; r < 4; r++) {
                int rowg = bm * BM + wr * (BM / 2) + fr * 16 + rg + r;
                float v = acc[fr][fc][r] + bv;
                if (RELU) v = fmaxf(v, 0.f);
                if (OUTBF16) ((bf16_t*)Cout)[(size_t)rowg * ldC + col] = (bf16_t)v;
                else         ((float*)Cout)[(size_t)rowg * ldC + col] = v;
            }
        }
    }
}

// ---------------- flash attention: swapped-QK^T 32x32, block-shared LDS (R13, proven) ----------------
// QK buffer is now [4096][1024] (Q cols 0-511, K cols 512-1023).
union BU { bf16x8 v; u32 d[4]; };

static __device__ __forceinline__ u32 pkbf(float a, float b)
{
    union { bf16_t h[2]; u32 w; } u;
    u.h[0] = (bf16_t)a; u.h[1] = (bf16_t)b;
    return u.w;
}

// permlane32_swap: x = {a.lo_lanes, b.lo_lanes}, y = {a.hi_lanes, b.hi_lanes}
static __device__ __forceinline__ void plswap(u32 a, u32 b, u32& x, u32& y)
{
#if __has_builtin(__builtin_amdgcn_permlane32_swap)
    u32x2 r = __builtin_amdgcn_permlane32_swap(a, b, false, false);
    x = r[0]; y = r[1];
#else
    const bool hi = (threadIdx.x & 32) != 0;
    u32 sb = __shfl_xor(b, 32), sa = __shfl_xor(a, 32);
    x = hi ? sb : a;
    y = hi ? b : sa;
#endif
}

// grid (16 qblocks, 16 bh, 4 kv-splits); 4 waves x 32 q-rows = 128 q/block; KVBLK=32.
__global__ __launch_bounds__(256)
void flash_kernel(const bf16_t* __restrict__ QK, const bf16_t* __restrict__ Vt,
                  bf16_t* __restrict__ Op01, bf16_t* __restrict__ Op23,
                  float2* __restrict__ ml)
{
    const int tid = threadIdx.x, lane = tid & 63, wid = tid >> 6;
    const int bh = blockIdx.y, b = bh >> 3, h = bh & 7;
    const int split = blockIdx.z;
    const int qbase = blockIdx.x * 128 + wid * 32;
    const int l31 = lane & 31, hi = lane >> 5;

    __shared__ __align__(16) bf16_t Kst[2][32 * KLD];
    __shared__ __align__(16) bf16_t Vst[2][64 * VLD];
    __shared__ __align__(16) bf16_t tlds[4][32 * 68];
    bf16_t* tw = &tlds[wid][0];

    const bf16_t* Qp = QK + (size_t)(b * 2048 + qbase + l31) * 1024 + h * 64 + hi * 8;
    const bf16_t* Kbase = QK + (size_t)(b * 2048) * 1024 + 512 + h * 64;
    const bf16_t* Vbase = Vt + (size_t)bh * 64 * 2048;

    const int kr = tid >> 3, kc = (tid & 7) * 8;
    const int vr = tid >> 2, vc = (tid & 3) * 8;

    bf16x8 qf[4];
#pragma unroll
    for (int t = 0; t < 4; t++)
        qf[t] = *(const bf16x8*)(Qp + t * 16);

    bf16x8 ones;
#pragma unroll
    for (int e = 0; e < 8; e++) ones[e] = (bf16_t)1.0f;

    f32x16 acc0 = {}, acc1 = {}, accS = {};
    float mrun = -1e30f;

    const int kv0 = split * 512;

    bf16x8 kreg = *(const bf16x8*)(Kbase + (size_t)(kv0 + kr) * 1024 + kc);
    bf16x8 vreg = *(const bf16x8*)(Vbase + (size_t)vr * 2048 + kv0 + vc);
    *(bf16x8*)&Kst[0][kr * KLD + kc] = kreg;
    *(bf16x8*)&Vst[0][vr * VLD + vc] = vreg;
    __syncthreads();

    int buf = 0;
#pragma unroll 2
    for (int kt = kv0; kt < kv0 + 512; kt += 32) {
        const bool nxt = (kt + 32 < kv0 + 512);
        if (nxt) {
            kreg = *(const bf16x8*)(Kbase + (size_t)(kt + 32 + kr) * 1024 + kc);
            vreg = *(const bf16x8*)(Vbase + (size_t)vr * 2048 + kt + 32 + vc);
        }

        bf16x8 kf[4];
#pragma unroll
        for (int t = 0; t < 4; t++)
            kf[t] = *(const bf16x8*)&Kst[buf][l31 * KLD + hi * 8 + t * 16];
        bf16x8 vf00 = *(const bf16x8*)&Vst[buf][l31 * VLD + hi * 8];
        bf16x8 vf01 = *(const bf16x8*)&Vst[buf][l31 * VLD + 16 + hi * 8];
        bf16x8 vf10 = *(const bf16x8*)&Vst[buf][(32 + l31) * VLD + hi * 8];
        bf16x8 vf11 = *(const bf16x8*)&Vst[buf][(32 + l31) * VLD + 16 + hi * 8];

        f32x16 p = {};
        __builtin_amdgcn_s_setprio(1);
        p = __builtin_amdgcn_mfma_f32_32x32x16_bf16(kf[0], qf[0], p, 0, 0, 0);
        p = __builtin_amdgcn_mfma_f32_32x32x16_bf16(kf[1], qf[1], p, 0, 0, 0);
        p = __builtin_amdgcn_mfma_f32_32x32x16_bf16(kf[2], qf[2], p, 0, 0, 0);
        p = __builtin_amdgcn_mfma_f32_32x32x16_bf16(kf[3], qf[3], p, 0, 0, 0);
        __builtin_amdgcn_s_setprio(0);

        float x0 = fmaxf(p[0], p[8]),  x1 = fmaxf(p[1], p[9]);
        float x2 = fmaxf(p[2], p[10]), x3 = fmaxf(p[3], p[11]);
        float x4 = fmaxf(p[4], p[12]), x5 = fmaxf(p[5], p[13]);
        float x6 = fmaxf(p[6], p[14]), x7 = fmaxf(p[7], p[15]);
        x0 = fmaxf(x0, x4); x1 = fmaxf(x1, x5); x2 = fmaxf(x2, x6); x3 = fmaxf(x3, x7);
        float cm = fmaxf(fmaxf(x0, x1), fmaxf(x2, x3));
        {
            u32 r0, r1;
            plswap(__float_as_uint(cm), __float_as_uint(cm), r0, r1);
            cm = fmaxf(__uint_as_float(r0), __uint_as_float(r1));
        }

        if (__any(cm > mrun + 12.0f)) {
            float mnew = fmaxf(mrun, cm);
            float fac = __builtin_amdgcn_exp2f(mrun - mnew);
#pragma unroll
            for (int i = 0; i < 16; i++) { acc0[i] *= fac; acc1[i] *= fac; accS[i] *= fac; }
            mrun = mnew;
        }

        float e[16];
#pragma unroll
        for (int i = 0; i < 16; i++) e[i] = __builtin_amdgcn_exp2f(p[i] - mrun);

        u32 pk0 = pkbf(e[0], e[1]),   pk1 = pkbf(e[2], e[3]);
        u32 pk2 = pkbf(e[4], e[5]),   pk3 = pkbf(e[6], e[7]);
        u32 pk4 = pkbf(e[8], e[9]),   pk5 = pkbf(e[10], e[11]);
        u32 pk6 = pkbf(e[12], e[13]), pk7 = pkbf(e[14], e[15]);
        BU b0, b1;
        plswap(pk0, pk2, b0.d[0], b0.d[2]);
        plswap(pk1, pk3, b0.d[1], b0.d[3]);
        plswap(pk4, pk6, b1.d[0], b1.d[2]);
        plswap(pk5, pk7, b1.d[1], b1.d[3]);

        __builtin_amdgcn_s_setprio(1);
        acc0 = __builtin_amdgcn_mfma_f32_32x32x16_bf16(vf00, b0.v, acc0, 0, 0, 0);
        acc0 = __builtin_amdgcn_mfma_f32_32x32x16_bf16(vf01, b1.v, acc0, 0, 0, 0);
        acc1 = __builtin_amdgcn_mfma_f32_32x32x16_bf16(vf10, b0.v, acc1, 0, 0, 0);
        acc1 = __builtin_amdgcn_mfma_f32_32x32x16_bf16(vf11, b1.v, acc1, 0, 0, 0);
        accS = __builtin_amdgcn_mfma_f32_32x32x16_bf16(ones, b0.v, accS, 0, 0, 0);
        accS = __builtin_amdgcn_mfma_f32_32x32x16_bf16(ones, b1.v, accS, 0, 0, 0);
        __builtin_amdgcn_s_setprio(0);

        if (nxt) {
            *(bf16x8*)&Kst[buf ^ 1][kr * KLD + kc] = kreg;
            *(bf16x8*)&Vst[buf ^ 1][vr * VLD + vc] = vreg;
        }
        __syncthreads();
        buf ^= 1;
    }

    const float lsum = accS[0];
    float inv = 1.f / lsum;
#pragma unroll
    for (int r = 0; r < 16; r++) {
        int drow = (r & 3) + 8 * (r >> 2) + 4 * hi;
        tw[l31 * 68 + drow]      = (bf16_t)(acc0[r] * inv);
        tw[l31 * 68 + 32 + drow] = (bf16_t)(acc1[r] * inv);
    }
    bf16_t* Op = (split < 2) ? Op01 + (size_t)split * SPLIT_ROWS * 64
                             : Op23 + (size_t)(split - 2) * SPLIT_ROWS * 64;
    const size_t rowbase = (size_t)bh * 2048 + qbase;
#pragma unroll
    for (int ps = 0; ps < 4; ps++) {
        int rr = (lane >> 3) + ps * 8;
        int cc = lane & 7;
        bf16x8 ov = *(const bf16x8*)&tw[rr * 68 + cc * 8];
        *(bf16x8*)(Op + (rowbase + rr) * 64 + cc * 8) = ov;
    }
    if (lane < 32)
        ml[(size_t)split * SPLIT_ROWS + rowbase + l31] = make_float2(mrun, lsum);
}

// ---------------- fused combine(4 splits) + residual-add + LayerNorm -> out1b bf16 ----------------
// NOTE: outb must NOT alias Op01/Op23 (R12 lesson: cross-block read/write race).
__global__ __launch_bounds__(128)
void combine_ln_kernel(const bf16_t* __restrict__ Op01, const bf16_t* __restrict__ Op23,
                       const float2* __restrict__ ml, const float* __restrict__ resid,
                       const float* __restrict__ g, const float* __restrict__ bta,
                       bf16_t* __restrict__ outb)
{
    const int row = blockIdx.x;            // b*2048 + q
    const int tid = threadIdx.x;
    const int b = row >> 11, q = row & 2047;
    const int d = tid * 4, h = d >> 6, dd = d & 63;
    const size_t prow = ((size_t)(b * 8 + h)) * 2048 + q;

    float2 m0 = ml[prow];
    float2 m1 = ml[SPLIT_ROWS + prow];
    float2 m2 = ml[2 * SPLIT_ROWS + prow];
    float2 m3 = ml[3 * SPLIT_ROWS + prow];
    float M = fmaxf(fmaxf(m0.x, m1.x), fmaxf(m2.x, m3.x));
    float w0 = m0.y * __builtin_amdgcn_exp2f(m0.x - M);
    float w1 = m1.y * __builtin_amdgcn_exp2f(m1.x - M);
    float w2 = m2.y * __builtin_amdgcn_exp2f(m2.x - M);
    float w3 = m3.y * __builtin_amdgcn_exp2f(m3.x - M);
    float winv = 1.f / (w0 + w1 + w2 + w3);

    bf16x4 p0 = *(const bf16x4*)(Op01 + prow * 64 + dd);
    bf16x4 p1 = *(const bf16x4*)(Op01 + (SPLIT_ROWS + prow) * 64 + dd);
    bf16x4 p2 = *(const bf16x4*)(Op23 + prow * 64 + dd);
    bf16x4 p3 = *(const bf16x4*)(Op23 + (SPLIT_ROWS + prow) * 64 + dd);
    float4 rv = ((const float4*)resid)[row * 128 + tid];

    float x0 = (w0 * (float)p0[0] + w1 * (float)p1[0] + w2 * (float)p2[0] + w3 * (float)p3[0]) * winv + rv.x;
    float x1 = (w0 * (float)p0[1] + w1 * (float)p1[1] + w2 * (float)p2[1] + w3 * (float)p3[1]) * winv + rv.y;
    float x2 = (w0 * (float)p0[2] + w1 * (float)p1[2] + w2 * (float)p2[2] + w3 * (float)p3[2]) * winv + rv.z;
    float x3 = (w0 * (float)p0[3] + w1 * (float)p1[3] + w2 * (float)p2[3] + w3 * (float)p3[3]) * winv + rv.w;

    float s = x0 + x1 + x2 + x3;
    float sq = x0 * x0 + x1 * x1 + x2 * x2 + x3 * x3;
#pragma unroll
    for (int dl = 1; dl < 64; dl <<= 1) { s += __shfl_xor(s, dl); sq += __shfl_xor(sq, dl); }
    __shared__ float red[2][2];
    const int wid = tid >> 6;
    if ((tid & 63) == 0) { red[wid][0] = s; red[wid][1] = sq; }
    __syncthreads();
    s = red[0][0] + red[1][0];
    sq = red[0][1] + red[1][1];
    float mu = s * (1.f / 512.f);
    float var = sq * (1.f / 512.f) - mu * mu;
    float rstd = rsqrtf(var + 1e-5f);
    const float4 gv = ((const float4*)g)[tid];
    const float4 bv = ((const float4*)bta)[tid];
    bf16x4 o;
    o[0] = (bf16_t)((x0 - mu) * rstd * gv.x + bv.x);
    o[1] = (bf16_t)((x1 - mu) * rstd * gv.y + bv.y);
    o[2] = (bf16_t)((x2 - mu) * rstd * gv.z + bv.z);
    o[3] = (bf16_t)((x3 - mu) * rstd * gv.w + bv.w);
    *(bf16x4*)(outb + (size_t)row * 512 + tid * 4) = o;
}

// ---------------- fused residual-add + LayerNorm (D=512) ----------------
template<bool RESBF>
__global__ __launch_bounds__(128)
void add_ln_kernel(const float* __restrict__ a, const void* __restrict__ res,
                   const float* __restrict__ g, const float* __restrict__ bta,
                   float* outf, bf16_t* outb)
{
    const int row = blockIdx.x, tid = threadIdx.x;
    const float4* a4 = (const float4*)(a + (size_t)row * 512);
    float4 av = a4[tid];
    float r0, r1, r2, r3;
    if (RESBF) {
        bf16x4 rv = ((const bf16x4*)res)[row * 128 + tid];
        r0 = (float)rv[0]; r1 = (float)rv[1]; r2 = (float)rv[2]; r3 = (float)rv[3];
    } else {
        float4 rv = ((const float4*)res)[row * 128 + tid];
        r0 = rv.x; r1 = rv.y; r2 = rv.z; r3 = rv.w;
    }
    float x0 = av.x + r0, x1 = av.y + r1, x2 = av.z + r2, x3 = av.w + r3;
    float s = x0 + x1 + x2 + x3;
    float sq = x0 * x0 + x1 * x1 + x2 * x2 + x3 * x3;
#pragma unroll
    for (int d = 1; d < 64; d <<= 1) { s += __shfl_xor(s, d); sq += __shfl_xor(sq, d); }
    __shared__ float red[2][2];
    const int wid = tid >> 6;
    if ((tid & 63) == 0) { red[wid][0] = s; red[wid][1] = sq; }
    __syncthreads();
    s = red[0][0] + red[1][0];
    sq = red[0][1] + red[1][1];
    float mu = s * (1.f / 512.f);
    float var = sq * (1.f / 512.f) - mu * mu;
    float rstd = rsqrtf(var + 1e-5f);
    const float4* g4 = (const float4*)g;
    const float4* b4 = (const float4*)bta;
    float4 gv = g4[tid], bv = b4[tid];
    float4 y;
    y.x = (x0 - mu) * rstd * gv.x + bv.x;
    y.y = (x1 - mu) * rstd * gv.y + bv.y;
    y.z = (x2 - mu) * rstd * gv.z + bv.z;
    y.w = (x3 - mu) * rstd * gv.w + bv.w;
    if (outf) ((float4*)(outf + (size_t)row * 512))[tid] = y;
    if (outb) {
        bf16x4 o;
        o[0] = (bf16_t)y.x; o[1] = (bf16_t)y.y; o[2] = (bf16_t)y.z; o[3] = (bf16_t)y.w;
        *(bf16x4*)(outb + (size_t)row * 512 + tid * 4) = o;
    }
}

// ---------------- orchestration ----------------
// Workspace arena (29.5 MB high-water; lifetime-safe aliasing):
//   0- 2 MB : W1t    (A->F)
//   2- 4 MB : W2t    (A->G)
//   4-12 MB : Xb(4-8)+Eb(8-12) (A->B); then Op01 splits 0-1 (D->E); then Hb[0:8MB] (F->G)
//  12-20 MB : QKb [4096][1024] (B->D); then Hb[8:16MB] (F->G)
//  24-28 MB : Vtb (B->D, written by QKV gemm); then out1b (E->H)
//  28-29.5  : Wqkvt  (A->B); then ml 1MB (4x32768 float2) (D->E)
// d_out: Op23 splits 2-3 (D->E); then FF f32 (G->H, in-place LN2).
extern "C" void kernel_launch(void* const* d_in, const int* in_sizes, int n_in,
                              void* d_out, int out_size, void* d_ws, size_t ws_size,
                              hipStream_t stream)
{
    const float* inputs = (const float*)d_in[0];
    const float* encx   = (const float*)d_in[1];
    const float* Wq     = (const float*)d_in[2];
    const float* Wk     = (const float*)d_in[3];
    const float* Wv     = (const float*)d_in[4];
    const float* ln1g   = (const float*)d_in[5];
    const float* ln1b   = (const float*)d_in[6];
    const float* W1     = (const float*)d_in[7];
    const float* b1     = (const float*)d_in[8];
    const float* W2     = (const float*)d_in[9];
    const float* b2     = (const float*)d_in[10];
    const float* ln2g   = (const float*)d_in[11];
    const float* ln2b   = (const float*)d_in[12];

    char* ws = (char*)d_ws;
    const size_t MB = 1u << 20;
    bf16_t* W1t   = (bf16_t*)(ws);
    bf16_t* W2t   = (bf16_t*)(ws + 2 * MB);
    bf16_t* Xb    = (bf16_t*)(ws + 4 * MB);
    bf16_t* Op01  = (bf16_t*)(ws + 4 * MB);       // 8 MB, aliases Xb+Eb (dead after QKV gemm)
    bf16_t* Hb    = (bf16_t*)(ws + 4 * MB);       // 16 MB @4-20, aliases Op01(dead after E)+QKb
    bf16_t* Eb    = (bf16_t*)(ws + 8 * MB);
    bf16_t* QKb   = (bf16_t*)(ws + 12 * MB);      // 8 MB [4096][1024]
    bf16_t* Vtb   = (bf16_t*)(ws + 24 * MB);
    bf16_t* out1b = (bf16_t*)(ws + 24 * MB);      // 4 MB, aliases Vtb (dead after flash)
    bf16_t* Wqkvt = (bf16_t*)(ws + 28 * MB);
    float2* mlbuf = (float2*)(ws + 28 * MB);      // 1 MB, aliases Wqkvt (dead after QKV gemm)
    bf16_t* Op23  = (bf16_t*)d_out;               // 8 MB, d_out unused until combine_ln
    float*  FF    = (float*)d_out;                // FF (G->H, consumed in-place by ln2)

    // A. merged prep: converts (Q folds 0.125*log2 e) + weight transposes, one dispatch
    prep_kernel<<<6912, 256, 0, stream>>>(inputs, Xb, 0.125f * 1.44269504f, encx, Eb,
                                          Wq, Wk, Wv, W1, W2, Wqkvt, W1t, W2t);
    // B. fused QKV projection with V-transpose epilogue: QK -> QKb [4096][1024], V -> Vtb
    gemm_kernel<64, 128, true, true, false, false, true><<<dim3(64, 12), 256, 0, stream>>>(
        Xb, Eb, 4, Wqkvt, nullptr, QKb, Vtb, 512, 1024);
    // D. flash attention (kv-split 4, 4-wave blocks — R13 proven) -> partials
    flash_kernel<<<dim3(16, 16, 4), 256, 0, stream>>>(QKb, Vtb, Op01, Op23, mlbuf);
    // E. fused combine + LN1: out1 = LN(O + inputs) -> bf16 at 24-28 MB
    combine_ln_kernel<<<4096, 128, 0, stream>>>(Op01, Op23, mlbuf, inputs, ln1g, ln1b, out1b);
    // F. H = relu(out1 @ W1 + b1)  [4096][2048]; 512 blocks = 2.0/CU
    gemm_kernel<128, 128, false, false, true, true, true><<<dim3(32, 16), 256, 0, stream>>>(
        out1b, nullptr, 0, W1t, b1, Hb, nullptr, 512, 2048);
    // G. FF = H @ W2 + b2  [4096][512]; 512 blocks = 2.0/CU
    gemm_kernel<64, 64, false, false, true, false, false><<<dim3(64, 8), 256, 0, stream>>>(
        Hb, nullptr, 0, W2t, b2, FF, nullptr, 2048, 512);
    // H. final = LN(FF + out1b) -> d_out (in-place, row-local)
    add_ln_kernel<true><<<4096, 128, 0, stream>>>(FF, out1b, ln2g, ln2b, (float*)d_out, nullptr);
}

// Round 18
// 117.179 us; speedup vs baseline: 1.2428x; 1.0330x over previous
//
#include <hip/hip_runtime.h>

typedef __bf16 bf16_t;
typedef __bf16 bf16x8 __attribute__((ext_vector_type(8)));
typedef __bf16 bf16x4 __attribute__((ext_vector_type(4)));
typedef float f32x4 __attribute__((ext_vector_type(4)));
typedef float f32x16 __attribute__((ext_vector_type(16)));
typedef unsigned int u32;
typedef unsigned int u32x2 __attribute__((ext_vector_type(2)));

#define GLB_AS(p) ((const __attribute__((address_space(1))) unsigned int*)(p))
#define LDS_AS(p) ((__attribute__((address_space(3))) unsigned int*)(p))

// rows per KV-split = 16 bh * 2048 q = 32768; 4 splits of 512 kv each
#define SPLIT_ROWS 32768
#define KLD 68   // K tile [32 kv][64 d] row stride (pad +4): ~0 conflicts (R9/R13-measured)
#define VLD 44   // V^T tile [64 d][32 kv] row stride (pad +12): ~0 conflicts (R9/R13-measured)

// ---------------- merged prep: fp32->bf16 converts (jobs 0-4095) + weight transposes (4096-6911) ----------------
__global__ void prep_kernel(const float* __restrict__ inputs, bf16_t* __restrict__ Xb, float scaleQ,
                            const float* __restrict__ encx, bf16_t* __restrict__ Eb,
                            const float* __restrict__ Wq, const float* __restrict__ Wk,
                            const float* __restrict__ Wv, const float* __restrict__ W1,
                            const float* __restrict__ W2, bf16_t* __restrict__ Wqkvt,
                            bf16_t* __restrict__ W1t, bf16_t* __restrict__ W2t)
{
    __shared__ float tile[32][33];
    const int bid = blockIdx.x;
    const int tid = threadIdx.x;
    if (bid < 4096) {
        const float* in;
        bf16_t* out;
        float scale;
        int i;
        if (bid < 2048) { in = inputs; out = Xb; scale = scaleQ; i = (bid * 256 + tid) * 4; }
        else            { in = encx;   out = Eb; scale = 1.0f;   i = ((bid - 2048) * 256 + tid) * 4; }
        float4 v = *(const float4*)(in + i);
        bf16x4 o;
        o[0] = (bf16_t)(v.x * scale); o[1] = (bf16_t)(v.y * scale);
        o[2] = (bf16_t)(v.z * scale); o[3] = (bf16_t)(v.w * scale);
        *(bf16x4*)(out + i) = o;
        return;
    }
    const int j = bid - 4096;
    const float* in;
    bf16_t* out;
    int R, C, bx, by;
    if (j < 768) {
        int k = j >> 8, l = j & 255;
        in = (k == 0) ? Wq : (k == 1) ? Wk : Wv;
        out = Wqkvt + k * 512 * 512;
        R = 512; C = 512; bx = l & 15; by = l >> 4;
    } else if (j < 1792) {
        int l = j - 768;
        in = W1; out = W1t; R = 512; C = 2048; bx = l % 64; by = l / 64;
    } else {
        int l = j - 1792;
        in = W2; out = W2t; R = 2048; C = 512; bx = l % 16; by = l / 16;
    }
    const int r0 = by * 32, c0 = bx * 32;
#pragma unroll
    for (int t = 0; t < 4; t++) {
        int r = t * 8 + (tid >> 5), c = tid & 31;
        tile[r][c] = in[(size_t)(r0 + r) * C + c0 + c];
    }
    __syncthreads();
#pragma unroll
    for (int t = 0; t < 4; t++) {
        int c = t * 8 + (tid >> 5), r = tid & 31;
        out[(size_t)(c0 + c) * R + r0 + r] = (bf16_t)tile[r][c];
    }
}

// ---------------- GEMM: C[M][N] = A[M][K] @ Bt[N][K]^T ----------------
// BM x BN tile, BK=32, 4 waves (2x2); 2-phase double-buffered LDS.
// VFUSE (QKV only, BM=64): bn 8-11 -> V cols written transposed to Vt[bh][64][2048].
template<int BM, int BN, bool SPLITA, bool VFUSE, bool BIAS, bool RELU, bool OUTBF16>
__global__ __launch_bounds__(256)
void gemm_kernel(const bf16_t* __restrict__ A0, const bf16_t* __restrict__ A1, int nsplit,
                 const bf16_t* __restrict__ Bt, const float* __restrict__ bias,
                 void* __restrict__ Cout, bf16_t* __restrict__ VtOut, int K, int ldC)
{
    constexpr int FR = BM / 32, FC = BN / 32;
    __shared__ __align__(16) bf16_t As[2][BM * 32];
    __shared__ __align__(16) bf16_t Bs[2][BN * 32];
    const int bm = blockIdx.x, bn = blockIdx.y;
    const bf16_t* A = (!SPLITA || bn < nsplit) ? A0 : A1;
    const int tid = threadIdx.x;
    const int lane = tid & 63;
    const int wid = tid >> 6;
    const int wr = wid >> 1, wc = wid & 1;

    f32x4 acc[FR][FC] = {};

    const int cb = wid * 2;
    const int lbB0 = (BN == 128 ? cb * 1024 : wid * 1024) + lane * 16;
    const int rowB0 = lbB0 >> 6, colB0 = (lbB0 & 63) >> 1;
    const int rowB1 = (lbB0 + 1024) >> 6, colB1 = ((lbB0 + 1024) & 63) >> 1;
    const int lbA0 = (BM == 128 ? cb * 1024 : wid * 1024) + lane * 16;
    const int rowA0 = lbA0 >> 6, colA0 = (lbA0 & 63) >> 1;
    const int rowA1 = (lbA0 + 1024) >> 6, colA1 = ((lbA0 + 1024) & 63) >> 1;

    const bf16_t* Abase = A + (size_t)(bm * BM) * K;
    const bf16_t* Bbase = Bt + (size_t)(bn * BN) * K;

    auto stage = [&](int k0, int b_) {
        if constexpr (BM == 128) {
            __builtin_amdgcn_global_load_lds(GLB_AS(Abase + (size_t)rowA0 * K + k0 + colA0), LDS_AS(&As[b_][cb * 512]), 16, 0, 0);
            __builtin_amdgcn_global_load_lds(GLB_AS(Abase + (size_t)rowA1 * K + k0 + colA1), LDS_AS(&As[b_][cb * 512 + 512]), 16, 0, 0);
        } else {
            __builtin_amdgcn_global_load_lds(GLB_AS(Abase + (size_t)rowA0 * K + k0 + colA0), LDS_AS(&As[b_][wid * 512]), 16, 0, 0);
        }
        if constexpr (BN == 128) {
            __builtin_amdgcn_global_load_lds(GLB_AS(Bbase + (size_t)rowB0 * K + k0 + colB0), LDS_AS(&Bs[b_][cb * 512]), 16, 0, 0);
            __builtin_amdgcn_global_load_lds(GLB_AS(Bbase + (size_t)rowB1 * K + k0 + colB1), LDS_AS(&Bs[b_][cb * 512 + 512]), 16, 0, 0);
        } else {
            __builtin_amdgcn_global_load_lds(GLB_AS(Bbase + (size_t)rowB0 * K + k0 + colB0), LDS_AS(&Bs[b_][wid * 512]), 16, 0, 0);
        }
    };

    stage(0, 0);
    __syncthreads();

    int cur = 0;
    for (int k0 = 0; k0 < K; k0 += 32) {
        if (k0 + 32 < K) stage(k0 + 32, cur ^ 1);

        bf16x8 af[FR], bfr[FC];
#pragma unroll
        for (int f = 0; f < FR; f++)
            af[f] = *(const bf16x8*)&As[cur][(wr * (BM / 2) + f * 16 + (lane & 15)) * 32 + (lane >> 4) * 8];
#pragma unroll
        for (int f = 0; f < FC; f++)
            bfr[f] = *(const bf16x8*)&Bs[cur][(wc * (BN / 2) + f * 16 + (lane & 15)) * 32 + (lane >> 4) * 8];
#pragma unroll
        for (int fr = 0; fr < FR; fr++)
#pragma unroll
            for (int fc = 0; fc < FC; fc++)
                acc[fr][fc] = __builtin_amdgcn_mfma_f32_16x16x32_bf16(af[fr], bfr[fc], acc[fr][fc], 0, 0, 0);

        __syncthreads();
        cur ^= 1;
    }

    const int rg = (lane >> 4) * 4, cl = lane & 15;
    if (VFUSE && bn >= 8) {
        // V block: write transposed to Vt[bh][64][2048]
#pragma unroll
        for (int fc = 0; fc < FC; fc++) {
            const int colv = (bn - 8) * BN + wc * (BN / 2) + fc * 16 + cl;  // 0-511
            const int h = colv >> 6, d = colv & 63;
#pragma unroll
            for (int fr = 0; fr < FR; fr++) {
                const int rowg = bm * BM + wr * (BM / 2) + fr * 16 + rg;    // base of 4
                const int b = rowg >> 11, lk = rowg & 2047;
                bf16x4 o;
#pragma unroll
                for (int r = 0; r < 4; r++) o[r] = (bf16_t)acc[fr][fc][r];
                *(bf16x4*)(VtOut + ((size_t)(b * 8 + h) * 64 + d) * 2048 + lk) = o;
            }
        }
        return;
    }
#pragma unroll
    for (int fc = 0; fc < FC; fc++) {
        const int col = bn * BN + wc * (BN / 2) + fc * 16 + cl;
        float bv = 0.f;
        if (BIAS) bv = bias[col];
#pragma unroll
        for (int fr = 0; fr < FR; fr++) {
#pragma unroll
            for (int r = 0; r < 4; r++) {
                int rowg = bm * BM + wr * (BM / 2) + fr * 16 + rg + r;
                float v = acc[fr][fc][r] + bv;
                if (RELU) v = fmaxf(v, 0.f);
                if (OUTBF16) ((bf16_t*)Cout)[(size_t)rowg * ldC + col] = (bf16_t)v;
                else         ((float*)Cout)[(size_t)rowg * ldC + col] = v;
            }
        }
    }
}

// ---------------- flash attention: swapped-QK^T 32x32, block-shared LDS (R13 math) ----------------
// R18: XCD-chunked block swizzle (T1) + setprio removed (m190: hurts lockstep waves).
union BU { bf16x8 v; u32 d[4]; };

static __device__ __forceinline__ u32 pkbf(float a, float b)
{
    union { bf16_t h[2]; u32 w; } u;
    u.h[0] = (bf16_t)a; u.h[1] = (bf16_t)b;
    return u.w;
}

// permlane32_swap: x = {a.lo_lanes, b.lo_lanes}, y = {a.hi_lanes, b.hi_lanes}
static __device__ __forceinline__ void plswap(u32 a, u32 b, u32& x, u32& y)
{
#if __has_builtin(__builtin_amdgcn_permlane32_swap)
    u32x2 r = __builtin_amdgcn_permlane32_swap(a, b, false, false);
    x = r[0]; y = r[1];
#else
    const bool hi = (threadIdx.x & 32) != 0;
    u32 sb = __shfl_xor(b, 32), sa = __shfl_xor(a, 32);
    x = hi ? sb : a;
    y = hi ? b : sa;
#endif
}

// launched as flat grid of 1024 blocks; logical (qb 16, bh 16, split 4) decoded from an
// XCD-chunked bijective swizzle: consecutive logical blocks (which share K/V tiles) land
// on the SAME XCD's L2 (1024 % 8 == 0 -> bijective; guide ERRATA #11 satisfied).
__global__ __launch_bounds__(256)
void flash_kernel(const bf16_t* __restrict__ QK, const bf16_t* __restrict__ Vt,
                  bf16_t* __restrict__ Op01, bf16_t* __restrict__ Op23,
                  float2* __restrict__ ml)
{
    const int tid = threadIdx.x, lane = tid & 63, wid = tid >> 6;
    // XCD swizzle: phys -> logical so that logical id runs contiguously within an XCD
    const int phys = blockIdx.x;
    const int logical = (phys & 7) * 128 + (phys >> 3);   // 1024 blocks, 8 XCDs, 128/XCD
    const int qb = logical & 15, bh = (logical >> 4) & 15, split = logical >> 8;
    const int b = bh >> 3, h = bh & 7;
    const int qbase = qb * 128 + wid * 32;
    const int l31 = lane & 31, hi = lane >> 5;

    __shared__ __align__(16) bf16_t Kst[2][32 * KLD];
    __shared__ __align__(16) bf16_t Vst[2][64 * VLD];
    __shared__ __align__(16) bf16_t tlds[4][32 * 68];
    bf16_t* tw = &tlds[wid][0];

    const bf16_t* Qp = QK + (size_t)(b * 2048 + qbase + l31) * 1024 + h * 64 + hi * 8;
    const bf16_t* Kbase = QK + (size_t)(b * 2048) * 1024 + 512 + h * 64;
    const bf16_t* Vbase = Vt + (size_t)bh * 64 * 2048;

    const int kr = tid >> 3, kc = (tid & 7) * 8;
    const int vr = tid >> 2, vc = (tid & 3) * 8;

    bf16x8 qf[4];
#pragma unroll
    for (int t = 0; t < 4; t++)
        qf[t] = *(const bf16x8*)(Qp + t * 16);

    bf16x8 ones;
#pragma unroll
    for (int e = 0; e < 8; e++) ones[e] = (bf16_t)1.0f;

    f32x16 acc0 = {}, acc1 = {}, accS = {};
    float mrun = -1e30f;

    const int kv0 = split * 512;

    bf16x8 kreg = *(const bf16x8*)(Kbase + (size_t)(kv0 + kr) * 1024 + kc);
    bf16x8 vreg = *(const bf16x8*)(Vbase + (size_t)vr * 2048 + kv0 + vc);
    *(bf16x8*)&Kst[0][kr * KLD + kc] = kreg;
    *(bf16x8*)&Vst[0][vr * VLD + vc] = vreg;
    __syncthreads();

    int buf = 0;
#pragma unroll 2
    for (int kt = kv0; kt < kv0 + 512; kt += 32) {
        const bool nxt = (kt + 32 < kv0 + 512);
        if (nxt) {
            kreg = *(const bf16x8*)(Kbase + (size_t)(kt + 32 + kr) * 1024 + kc);
            vreg = *(const bf16x8*)(Vbase + (size_t)vr * 2048 + kt + 32 + vc);
        }

        bf16x8 kf[4];
#pragma unroll
        for (int t = 0; t < 4; t++)
            kf[t] = *(const bf16x8*)&Kst[buf][l31 * KLD + hi * 8 + t * 16];
        bf16x8 vf00 = *(const bf16x8*)&Vst[buf][l31 * VLD + hi * 8];
        bf16x8 vf01 = *(const bf16x8*)&Vst[buf][l31 * VLD + 16 + hi * 8];
        bf16x8 vf10 = *(const bf16x8*)&Vst[buf][(32 + l31) * VLD + hi * 8];
        bf16x8 vf11 = *(const bf16x8*)&Vst[buf][(32 + l31) * VLD + 16 + hi * 8];

        f32x16 p = {};
        p = __builtin_amdgcn_mfma_f32_32x32x16_bf16(kf[0], qf[0], p, 0, 0, 0);
        p = __builtin_amdgcn_mfma_f32_32x32x16_bf16(kf[1], qf[1], p, 0, 0, 0);
        p = __builtin_amdgcn_mfma_f32_32x32x16_bf16(kf[2], qf[2], p, 0, 0, 0);
        p = __builtin_amdgcn_mfma_f32_32x32x16_bf16(kf[3], qf[3], p, 0, 0, 0);

        float x0 = fmaxf(p[0], p[8]),  x1 = fmaxf(p[1], p[9]);
        float x2 = fmaxf(p[2], p[10]), x3 = fmaxf(p[3], p[11]);
        float x4 = fmaxf(p[4], p[12]), x5 = fmaxf(p[5], p[13]);
        float x6 = fmaxf(p[6], p[14]), x7 = fmaxf(p[7], p[15]);
        x0 = fmaxf(x0, x4); x1 = fmaxf(x1, x5); x2 = fmaxf(x2, x6); x3 = fmaxf(x3, x7);
        float cm = fmaxf(fmaxf(x0, x1), fmaxf(x2, x3));
        {
            u32 r0, r1;
            plswap(__float_as_uint(cm), __float_as_uint(cm), r0, r1);
            cm = fmaxf(__uint_as_float(r0), __uint_as_float(r1));
        }

        if (__any(cm > mrun + 12.0f)) {
            float mnew = fmaxf(mrun, cm);
            float fac = __builtin_amdgcn_exp2f(mrun - mnew);
#pragma unroll
            for (int i = 0; i < 16; i++) { acc0[i] *= fac; acc1[i] *= fac; accS[i] *= fac; }
            mrun = mnew;
        }

        float e[16];
#pragma unroll
        for (int i = 0; i < 16; i++) e[i] = __builtin_amdgcn_exp2f(p[i] - mrun);

        u32 pk0 = pkbf(e[0], e[1]),   pk1 = pkbf(e[2], e[3]);
        u32 pk2 = pkbf(e[4], e[5]),   pk3 = pkbf(e[6], e[7]);
        u32 pk4 = pkbf(e[8], e[9]),   pk5 = pkbf(e[10], e[11]);
        u32 pk6 = pkbf(e[12], e[13]), pk7 = pkbf(e[14], e[15]);
        BU b0, b1;
        plswap(pk0, pk2, b0.d[0], b0.d[2]);
        plswap(pk1, pk3, b0.d[1], b0.d[3]);
        plswap(pk4, pk6, b1.d[0], b1.d[2]);
        plswap(pk5, pk7, b1.d[1], b1.d[3]);

        acc0 = __builtin_amdgcn_mfma_f32_32x32x16_bf16(vf00, b0.v, acc0, 0, 0, 0);
        acc0 = __builtin_amdgcn_mfma_f32_32x32x16_bf16(vf01, b1.v, acc0, 0, 0, 0);
        acc1 = __builtin_amdgcn_mfma_f32_32x32x16_bf16(vf10, b0.v, acc1, 0, 0, 0);
        acc1 = __builtin_amdgcn_mfma_f32_32x32x16_bf16(vf11, b1.v, acc1, 0, 0, 0);
        accS = __builtin_amdgcn_mfma_f32_32x32x16_bf16(ones, b0.v, accS, 0, 0, 0);
        accS = __builtin_amdgcn_mfma_f32_32x32x16_bf16(ones, b1.v, accS, 0, 0, 0);

        if (nxt) {
            *(bf16x8*)&Kst[buf ^ 1][kr * KLD + kc] = kreg;
            *(bf16x8*)&Vst[buf ^ 1][vr * VLD + vc] = vreg;
        }
        __syncthreads();
        buf ^= 1;
    }

    const float lsum = accS[0];
    float inv = 1.f / lsum;
#pragma unroll
    for (int r = 0; r < 16; r++) {
        int drow = (r & 3) + 8 * (r >> 2) + 4 * hi;
        tw[l31 * 68 + drow]      = (bf16_t)(acc0[r] * inv);
        tw[l31 * 68 + 32 + drow] = (bf16_t)(acc1[r] * inv);
    }
    bf16_t* Op = (split < 2) ? Op01 + (size_t)split * SPLIT_ROWS * 64
                             : Op23 + (size_t)(split - 2) * SPLIT_ROWS * 64;
    const size_t rowbase = (size_t)bh * 2048 + qbase;
#pragma unroll
    for (int ps = 0; ps < 4; ps++) {
        int rr = (lane >> 3) + ps * 8;
        int cc = lane & 7;
        bf16x8 ov = *(const bf16x8*)&tw[rr * 68 + cc * 8];
        *(bf16x8*)(Op + (rowbase + rr) * 64 + cc * 8) = ov;
    }
    if (lane < 32)
        ml[(size_t)split * SPLIT_ROWS + rowbase + l31] = make_float2(mrun, lsum);
}

// ---------------- fused combine(4 splits) + residual-add + LayerNorm -> out1b bf16 ----------------
// NOTE: outb must NOT alias Op01/Op23 (R12 lesson: cross-block read/write race).
__global__ __launch_bounds__(128)
void combine_ln_kernel(const bf16_t* __restrict__ Op01, const bf16_t* __restrict__ Op23,
                       const float2* __restrict__ ml, const float* __restrict__ resid,
                       const float* __restrict__ g, const float* __restrict__ bta,
                       bf16_t* __restrict__ outb)
{
    const int row = blockIdx.x;            // b*2048 + q
    const int tid = threadIdx.x;
    const int b = row >> 11, q = row & 2047;
    const int d = tid * 4, h = d >> 6, dd = d & 63;
    const size_t prow = ((size_t)(b * 8 + h)) * 2048 + q;

    float2 m0 = ml[prow];
    float2 m1 = ml[SPLIT_ROWS + prow];
    float2 m2 = ml[2 * SPLIT_ROWS + prow];
    float2 m3 = ml[3 * SPLIT_ROWS + prow];
    float M = fmaxf(fmaxf(m0.x, m1.x), fmaxf(m2.x, m3.x));
    float w0 = m0.y * __builtin_amdgcn_exp2f(m0.x - M);
    float w1 = m1.y * __builtin_amdgcn_exp2f(m1.x - M);
    float w2 = m2.y * __builtin_amdgcn_exp2f(m2.x - M);
    float w3 = m3.y * __builtin_amdgcn_exp2f(m3.x - M);
    float winv = 1.f / (w0 + w1 + w2 + w3);

    bf16x4 p0 = *(const bf16x4*)(Op01 + prow * 64 + dd);
    bf16x4 p1 = *(const bf16x4*)(Op01 + (SPLIT_ROWS + prow) * 64 + dd);
    bf16x4 p2 = *(const bf16x4*)(Op23 + prow * 64 + dd);
    bf16x4 p3 = *(const bf16x4*)(Op23 + (SPLIT_ROWS + prow) * 64 + dd);
    float4 rv = ((const float4*)resid)[row * 128 + tid];

    float x0 = (w0 * (float)p0[0] + w1 * (float)p1[0] + w2 * (float)p2[0] + w3 * (float)p3[0]) * winv + rv.x;
    float x1 = (w0 * (float)p0[1] + w1 * (float)p1[1] + w2 * (float)p2[1] + w3 * (float)p3[1]) * winv + rv.y;
    float x2 = (w0 * (float)p0[2] + w1 * (float)p1[2] + w2 * (float)p2[2] + w3 * (float)p3[2]) * winv + rv.z;
    float x3 = (w0 * (float)p0[3] + w1 * (float)p1[3] + w2 * (float)p2[3] + w3 * (float)p3[3]) * winv + rv.w;

    float s = x0 + x1 + x2 + x3;
    float sq = x0 * x0 + x1 * x1 + x2 * x2 + x3 * x3;
#pragma unroll
    for (int dl = 1; dl < 64; dl <<= 1) { s += __shfl_xor(s, dl); sq += __shfl_xor(sq, dl); }
    __shared__ float red[2][2];
    const int wid = tid >> 6;
    if ((tid & 63) == 0) { red[wid][0] = s; red[wid][1] = sq; }
    __syncthreads();
    s = red[0][0] + red[1][0];
    sq = red[0][1] + red[1][1];
    float mu = s * (1.f / 512.f);
    float var = sq * (1.f / 512.f) - mu * mu;
    float rstd = rsqrtf(var + 1e-5f);
    const float4 gv = ((const float4*)g)[tid];
    const float4 bv = ((const float4*)bta)[tid];
    bf16x4 o;
    o[0] = (bf16_t)((x0 - mu) * rstd * gv.x + bv.x);
    o[1] = (bf16_t)((x1 - mu) * rstd * gv.y + bv.y);
    o[2] = (bf16_t)((x2 - mu) * rstd * gv.z + bv.z);
    o[3] = (bf16_t)((x3 - mu) * rstd * gv.w + bv.w);
    *(bf16x4*)(outb + (size_t)row * 512 + tid * 4) = o;
}

// ---------------- fused residual-add + LayerNorm (D=512): a bf16 + res bf16 -> f32 out ----------------
__global__ __launch_bounds__(128)
void add_ln_kernel(const bf16_t* __restrict__ a, const bf16_t* __restrict__ res,
                   const float* __restrict__ g, const float* __restrict__ bta,
                   float* __restrict__ outf)
{
    const int row = blockIdx.x, tid = threadIdx.x;
    bf16x4 av = ((const bf16x4*)a)[row * 128 + tid];
    bf16x4 rv = ((const bf16x4*)res)[row * 128 + tid];
    float x0 = (float)av[0] + (float)rv[0];
    float x1 = (float)av[1] + (float)rv[1];
    float x2 = (float)av[2] + (float)rv[2];
    float x3 = (float)av[3] + (float)rv[3];
    float s = x0 + x1 + x2 + x3;
    float sq = x0 * x0 + x1 * x1 + x2 * x2 + x3 * x3;
#pragma unroll
    for (int d = 1; d < 64; d <<= 1) { s += __shfl_xor(s, d); sq += __shfl_xor(sq, d); }
    __shared__ float red[2][2];
    const int wid = tid >> 6;
    if ((tid & 63) == 0) { red[wid][0] = s; red[wid][1] = sq; }
    __syncthreads();
    s = red[0][0] + red[1][0];
    sq = red[0][1] + red[1][1];
    float mu = s * (1.f / 512.f);
    float var = sq * (1.f / 512.f) - mu * mu;
    float rstd = rsqrtf(var + 1e-5f);
    const float4 gv = ((const float4*)g)[tid];
    const float4 bv = ((const float4*)bta)[tid];
    float4 y;
    y.x = (x0 - mu) * rstd * gv.x + bv.x;
    y.y = (x1 - mu) * rstd * gv.y + bv.y;
    y.z = (x2 - mu) * rstd * gv.z + bv.z;
    y.w = (x3 - mu) * rstd * gv.w + bv.w;
    ((float4*)(outf + (size_t)row * 512))[tid] = y;
}

// ---------------- orchestration ----------------
// Workspace arena (29.5 MB high-water; lifetime-safe aliasing):
//   0- 2 MB : W1t    (A->F)
//   2- 4 MB : W2t    (A->G)
//   4-12 MB : Xb(4-8)+Eb(8-12) (A->B); then Op01 splits 0-1 (D->E); then Hb[0:8MB] (F->G)
//  12-20 MB : QKb [4096][1024] (B->D); then Hb[8:16MB] (F->G)
//  20-24 MB : FFb bf16 (G->H)  <-- free until G
//  24-28 MB : Vtb (B->D, written by QKV gemm); then out1b (E->H)
//  28-29.5  : Wqkvt  (A->B); then ml 1MB (4x32768 float2) (D->E)
// d_out: Op23 splits 2-3 (D->E); then final f32 out (H).
extern "C" void kernel_launch(void* const* d_in, const int* in_sizes, int n_in,
                              void* d_out, int out_size, void* d_ws, size_t ws_size,
                              hipStream_t stream)
{
    const float* inputs = (const float*)d_in[0];
    const float* encx   = (const float*)d_in[1];
    const float* Wq     = (const float*)d_in[2];
    const float* Wk     = (const float*)d_in[3];
    const float* Wv     = (const float*)d_in[4];
    const float* ln1g   = (const float*)d_in[5];
    const float* ln1b   = (const float*)d_in[6];
    const float* W1     = (const float*)d_in[7];
    const float* b1     = (const float*)d_in[8];
    const float* W2     = (const float*)d_in[9];
    const float* b2     = (const float*)d_in[10];
    const float* ln2g   = (const float*)d_in[11];
    const float* ln2b   = (const float*)d_in[12];

    char* ws = (char*)d_ws;
    const size_t MB = 1u << 20;
    bf16_t* W1t   = (bf16_t*)(ws);
    bf16_t* W2t   = (bf16_t*)(ws + 2 * MB);
    bf16_t* Xb    = (bf16_t*)(ws + 4 * MB);
    bf16_t* Op01  = (bf16_t*)(ws + 4 * MB);       // 8 MB, aliases Xb+Eb (dead after QKV gemm)
    bf16_t* Hb    = (bf16_t*)(ws + 4 * MB);       // 16 MB @4-20, aliases Op01(dead after E)+QKb
    bf16_t* Eb    = (bf16_t*)(ws + 8 * MB);
    bf16_t* QKb   = (bf16_t*)(ws + 12 * MB);      // 8 MB [4096][1024]
    bf16_t* FFb   = (bf16_t*)(ws + 20 * MB);      // 4 MB bf16 FF (G->H)
    bf16_t* Vtb   = (bf16_t*)(ws + 24 * MB);
    bf16_t* out1b = (bf16_t*)(ws + 24 * MB);      // 4 MB, aliases Vtb (dead after flash)
    bf16_t* Wqkvt = (bf16_t*)(ws + 28 * MB);
    float2* mlbuf = (float2*)(ws + 28 * MB);      // 1 MB, aliases Wqkvt (dead after QKV gemm)
    bf16_t* Op23  = (bf16_t*)d_out;               // 8 MB, d_out unused until combine_ln

    // A. merged prep: converts (Q folds 0.125*log2 e) + weight transposes, one dispatch
    prep_kernel<<<6912, 256, 0, stream>>>(inputs, Xb, 0.125f * 1.44269504f, encx, Eb,
                                          Wq, Wk, Wv, W1, W2, Wqkvt, W1t, W2t);
    // B. fused QKV projection with V-transpose epilogue: QK -> QKb [4096][1024], V -> Vtb
    gemm_kernel<64, 128, true, true, false, false, true><<<dim3(64, 12), 256, 0, stream>>>(
        Xb, Eb, 4, Wqkvt, nullptr, QKb, Vtb, 512, 1024);
    // D. flash attention (kv-split 4, XCD-swizzled flat grid) -> partials
    flash_kernel<<<1024, 256, 0, stream>>>(QKb, Vtb, Op01, Op23, mlbuf);
    // E. fused combine + LN1: out1 = LN(O + inputs) -> bf16 at 24-28 MB
    combine_ln_kernel<<<4096, 128, 0, stream>>>(Op01, Op23, mlbuf, inputs, ln1g, ln1b, out1b);
    // F. H = relu(out1 @ W1 + b1)  [4096][2048]; 512 blocks = 2.0/CU
    gemm_kernel<128, 128, false, false, true, true, true><<<dim3(32, 16), 256, 0, stream>>>(
        out1b, nullptr, 0, W1t, b1, Hb, nullptr, 512, 2048);
    // G. FF = H @ W2 + b2  [4096][512] -> bf16 at 20-24 MB; 512 blocks = 2.0/CU
    gemm_kernel<64, 64, false, false, true, false, true><<<dim3(64, 8), 256, 0, stream>>>(
        Hb, nullptr, 0, W2t, b2, FFb, nullptr, 2048, 512);
    // H. final = LN(FFb + out1b) -> d_out f32
    add_ln_kernel<<<4096, 128, 0, stream>>>(FFb, out1b, ln2g, ln2b, (float*)d_out);
}